// Round 1
// baseline (1235.723 us; speedup 1.0000x reference)
//
#include <hip/hip_runtime.h>
#include <hip/hip_bf16.h>
#include <stdint.h>

#define BATCH   2
#define SEQLEN  4096
#define DMODEL  768
#define DSTATE  64
#define DCONV   4
#define HEADDIM 128
#define NHEADS  12
#define DINNER  1536
#define DINPROJ 3212
#define CONVDIM 1664
#define NPAD1   3328            // 26*128, padded N for GEMM1 B-operand
#define ROWS    (BATCH*SEQLEN)  // 8192

typedef __bf16 bf16x8 __attribute__((ext_vector_type(8)));
typedef float  f32x4  __attribute__((ext_vector_type(4)));

__device__ __forceinline__ void load_lds16(const void* g, void* l) {
    __builtin_amdgcn_global_load_lds(
        (const __attribute__((address_space(1))) unsigned int*)g,
        (__attribute__((address_space(3))) unsigned int*)l, 16, 0, 0);
}

// ---------------- conversion kernels ----------------
__global__ void cvt_bf16_kernel(const float* __restrict__ src,
                                __hip_bfloat16* __restrict__ dst, int n) {
    int i = (blockIdx.x * blockDim.x + threadIdx.x) * 4;
    if (i + 3 < n) {
        float4 v = *(const float4*)(src + i);
        dst[i + 0] = __float2bfloat16(v.x);
        dst[i + 1] = __float2bfloat16(v.y);
        dst[i + 2] = __float2bfloat16(v.z);
        dst[i + 3] = __float2bfloat16(v.w);
    } else {
        for (; i < n; ++i) dst[i] = __float2bfloat16(src[i]);
    }
}

__global__ void padw1_kernel(const float* __restrict__ src,
                             __hip_bfloat16* __restrict__ dst) {
    int i = blockIdx.x * blockDim.x + threadIdx.x;
    if (i >= NPAD1 * DMODEL) return;
    int r = i / DMODEL;
    float v = (r < DINPROJ) ? src[i] : 0.f;   // src flat idx == i for r<DINPROJ
    dst[i] = __float2bfloat16(v);
}

// ---------------- bf16 MFMA GEMM: C = A(MxK) * Bt(NxK)^T  (m97 structure) ----
__global__ __launch_bounds__(256) void gemm_bf16_nt(
    const __hip_bfloat16* __restrict__ A,
    const __hip_bfloat16* __restrict__ Bt,
    float* __restrict__ C,
    int M, int Nreal, int K, int ldc)
{
    __shared__ __align__(16) __hip_bfloat16 As[128 * 32];
    __shared__ __align__(16) __hip_bfloat16 Bs[128 * 32];
    const int tid  = threadIdx.x;
    const int lane = tid & 63;
    const int wave = tid >> 6;
    const int wm   = wave >> 1;   // 2x2 wave grid, each wave 64x64 output
    const int wn   = wave & 1;
    const int tm   = blockIdx.x * 128;
    const int tn   = blockIdx.y * 128;

    f32x4 acc[4][4] = {};

    const int lrow = tid >> 2;           // 0..63
    const int lk8  = (tid & 3) * 8;      // k element offset of 8-chunk
    const __hip_bfloat16* gA0 = A  + (size_t)(tm + lrow)      * K + lk8;
    const __hip_bfloat16* gA1 = A  + (size_t)(tm + lrow + 64) * K + lk8;
    const __hip_bfloat16* gB0 = Bt + (size_t)(tn + lrow)      * K + lk8;
    const __hip_bfloat16* gB1 = Bt + (size_t)(tn + lrow + 64) * K + lk8;
    __hip_bfloat16* sA0 = As + tid * 8;
    __hip_bfloat16* sA1 = As + tid * 8 + 2048;
    __hip_bfloat16* sB0 = Bs + tid * 8;
    __hip_bfloat16* sB1 = Bs + tid * 8 + 2048;

    const int fr = lane & 15;            // A row / B col within fragment
    const int fk = (lane >> 4) * 8;      // k offset within fragment

    for (int kk = 0; kk < K; kk += 32) {
        load_lds16(gA0 + kk, sA0);
        load_lds16(gA1 + kk, sA1);
        load_lds16(gB0 + kk, sB0);
        load_lds16(gB1 + kk, sB1);
        __syncthreads();
        bf16x8 af[4], bfr[4];
#pragma unroll
        for (int i = 0; i < 4; ++i) {
            af[i]  = *(const bf16x8*)(As + (wm * 64 + i * 16 + fr) * 32 + fk);
            bfr[i] = *(const bf16x8*)(Bs + (wn * 64 + i * 16 + fr) * 32 + fk);
        }
#pragma unroll
        for (int mi = 0; mi < 4; ++mi)
#pragma unroll
            for (int ni = 0; ni < 4; ++ni)
                acc[mi][ni] = __builtin_amdgcn_mfma_f32_16x16x32_bf16(
                    af[mi], bfr[ni], acc[mi][ni], 0, 0, 0);
        __syncthreads();
    }

    const int rq = (lane >> 4) * 4;      // C/D: row=(lane>>4)*4+j, col=lane&15
#pragma unroll
    for (int mi = 0; mi < 4; ++mi) {
#pragma unroll
        for (int ni = 0; ni < 4; ++ni) {
            int col = tn + wn * 64 + ni * 16 + fr;
            if (col < Nreal) {
                size_t rbase = (size_t)(tm + wm * 64 + mi * 16 + rq) * ldc + col;
#pragma unroll
                for (int j = 0; j < 4; ++j)
                    C[rbase + (size_t)j * ldc] = acc[mi][ni][j];
            }
        }
    }
}

// ---------------- depthwise causal conv (D_CONV=4) + SiLU + split -----------
__global__ void conv_kernel(const float* __restrict__ zx,
                            const float* __restrict__ convw,
                            const float* __restrict__ convb,
                            float* __restrict__ xbuf,
                            float* __restrict__ Bm,
                            float* __restrict__ Cm)
{
    int c = blockIdx.x * 256 + threadIdx.x;
    if (c >= CONVDIM) return;
    int row = blockIdx.y;               // b*L + l
    int l = row & (SEQLEN - 1);
    float acc = convb[c];
#pragma unroll
    for (int k = 0; k < 4; ++k) {
        int lt = l - 3 + k;
        if (lt >= 0)
            acc += zx[(size_t)(row - 3 + k) * DINPROJ + DINNER + c] * convw[c * 4 + k];
    }
    float v = acc / (1.f + expf(-acc)); // silu
    if (c < DINNER)               xbuf[(size_t)row * DINNER + c] = v;
    else if (c < DINNER + DSTATE) Bm[(size_t)row * DSTATE + (c - DINNER)] = v;
    else                          Cm[(size_t)row * DSTATE + (c - DINNER - DSTATE)] = v;
}

// ---------------- dt softplus + dA ----------------
__global__ void dt_kernel(const float* __restrict__ zx,
                          const float* __restrict__ dt_bias,
                          const float* __restrict__ A_log,
                          float* __restrict__ dtb, float* __restrict__ dAb)
{
    int i = blockIdx.x * 256 + threadIdx.x;
    if (i >= ROWS * NHEADS) return;
    int row = i / NHEADS, h = i - row * NHEADS;
    float v = zx[(size_t)row * DINPROJ + DINNER + CONVDIM + h] + dt_bias[h];
    float dt = (v > 20.f) ? v : log1pf(expf(v));
    float A = -expf(A_log[h]);
    dtb[i] = dt;
    dAb[i] = expf(dt * A);
}

// ---------------- selective scan -------------------
// grid = B * NHEADS * 8 p-slices = 192 blocks, 256 threads.
// thread owns p = p0 + (tid>>4), n = (tid&15)*4 .. +4  (4 states in regs)
#define NT 64
__global__ __launch_bounds__(256) void scan_kernel(
    const float* __restrict__ xbuf,   // (ROWS, 12, 128)
    const float* __restrict__ Bm,     // (ROWS, 64)
    const float* __restrict__ Cm,     // (ROWS, 64)
    const float* __restrict__ dtb,    // (ROWS, 12)
    const float* __restrict__ dAb,    // (ROWS, 12)
    const float* __restrict__ Dp,     // (12)
    float* __restrict__ ybuf)         // (ROWS, 12, 128)
{
    int blk = blockIdx.x;
    int ps = blk & 7;
    int h  = (blk >> 3) % NHEADS;
    int b  = blk / (NHEADS * 8);
    int p0 = ps * 16;
    int tid = threadIdx.x;
    int pl  = tid >> 4;         // 0..15
    int n0  = (tid & 15) * 4;

    __shared__ __align__(16) float lB[NT][64];
    __shared__ __align__(16) float lC[NT][64];
    __shared__ __align__(16) float lDtx[NT][16];
    __shared__ float lDA[NT];
    __shared__ float lY[NT][16];

    float s0 = 0.f, s1 = 0.f, s2 = 0.f, s3 = 0.f;
    float dph = Dp[h];
    size_t rowbase = (size_t)b * SEQLEN;

    for (int t0 = 0; t0 < SEQLEN; t0 += NT) {
        // stage B, C (64 x 64 floats each, coalesced float4)
        for (int i = tid; i < NT * 64 / 4; i += 256) {
            ((float4*)&lB[0][0])[i] = ((const float4*)Bm)[(rowbase + t0) * 16 + i];
            ((float4*)&lC[0][0])[i] = ((const float4*)Cm)[(rowbase + t0) * 16 + i];
        }
        // stage dtx = dt * x  (64 t x 16 p)
        for (int i = tid; i < NT * 16; i += 256) {
            int t = i >> 4, pp = i & 15;
            size_t r = rowbase + t0 + t;
            lDtx[t][pp] = dtb[r * NHEADS + h] * xbuf[(r * NHEADS + h) * HEADDIM + p0 + pp];
        }
        if (tid < NT) lDA[tid] = dAb[(rowbase + t0 + tid) * NHEADS + h];
        __syncthreads();

        for (int t = 0; t < NT; ++t) {
            float da  = lDA[t];
            float dtx = lDtx[t][pl];
            const float* bp = &lB[t][n0];
            const float* cp = &lC[t][n0];
            s0 = s0 * da + dtx * bp[0];
            s1 = s1 * da + dtx * bp[1];
            s2 = s2 * da + dtx * bp[2];
            s3 = s3 * da + dtx * bp[3];
            float part = s0 * cp[0] + s1 * cp[1] + s2 * cp[2] + s3 * cp[3];
            part += __shfl_xor(part, 1);
            part += __shfl_xor(part, 2);
            part += __shfl_xor(part, 4);
            part += __shfl_xor(part, 8);
            if ((tid & 15) == 0) lY[t][pl] = part;
        }
        __syncthreads();

        // write y (+ Dp * x)
        for (int i = tid; i < NT * 16; i += 256) {
            int t = i >> 4, pp = i & 15;
            size_t r = rowbase + t0 + t;
            size_t gi = (r * NHEADS + h) * HEADDIM + p0 + pp;
            ybuf[gi] = lY[t][pp] + dph * xbuf[gi];
        }
        __syncthreads();
    }
}

// ---------------- gate (y * silu(z)) + RMSNorm -> bf16 ----------------------
__global__ __launch_bounds__(256) void gate_rms_kernel(
    const float* __restrict__ ybuf, const float* __restrict__ zx,
    const float* __restrict__ norm_w, __hip_bfloat16* __restrict__ gbf)
{
    int row = blockIdx.x;
    int tid = threadIdx.x;
    const float* y = ybuf + (size_t)row * DINNER;
    const float* z = zx + (size_t)row * DINPROJ;
    float g[6];
    float ss = 0.f;
#pragma unroll
    for (int j = 0; j < 6; ++j) {
        int idx = tid + j * 256;
        float zz = z[idx];
        float gv = y[idx] * (zz / (1.f + expf(-zz)));
        g[j] = gv;
        ss += gv * gv;
    }
#pragma unroll
    for (int m = 1; m < 64; m <<= 1) ss += __shfl_xor(ss, m);
    __shared__ float red[4];
    if ((tid & 63) == 0) red[tid >> 6] = ss;
    __syncthreads();
    float tot = red[0] + red[1] + red[2] + red[3];
    float scale = rsqrtf(tot * (1.f / DINNER) + 1e-5f);
#pragma unroll
    for (int j = 0; j < 6; ++j) {
        int idx = tid + j * 256;
        gbf[(size_t)row * DINNER + idx] = __float2bfloat16(g[j] * scale * norm_w[idx]);
    }
}

// ---------------- launch ----------------
extern "C" void kernel_launch(void* const* d_in, const int* in_sizes, int n_in,
                              void* d_out, int out_size, void* d_ws, size_t ws_size,
                              hipStream_t stream)
{
    const float* u       = (const float*)d_in[0];
    const float* W_in    = (const float*)d_in[1];
    const float* conv_w  = (const float*)d_in[2];
    const float* conv_b  = (const float*)d_in[3];
    const float* dt_bias = (const float*)d_in[4];
    const float* A_log   = (const float*)d_in[5];
    const float* Dp      = (const float*)d_in[6];
    const float* norm_w  = (const float*)d_in[7];
    const float* W_out   = (const float*)d_in[8];
    float* out = (float*)d_out;

    char* ws = (char*)d_ws;
    size_t off = 0;
    auto alloc = [&](size_t bytes) {
        char* p = ws + off;
        off += (bytes + 255) & ~(size_t)255;
        return p;
    };
    __hip_bfloat16* ubf  = (__hip_bfloat16*)alloc((size_t)ROWS * DMODEL * 2);
    __hip_bfloat16* W1bf = (__hip_bfloat16*)alloc((size_t)NPAD1 * DMODEL * 2);
    __hip_bfloat16* W2bf = (__hip_bfloat16*)alloc((size_t)DMODEL * DINNER * 2);
    float* zx   = (float*)alloc((size_t)ROWS * DINPROJ * 4);
    float* xbuf = (float*)alloc((size_t)ROWS * DINNER * 4);
    float* Bmb  = (float*)alloc((size_t)ROWS * DSTATE * 4);
    float* Cmb  = (float*)alloc((size_t)ROWS * DSTATE * 4);
    float* dtb  = (float*)alloc((size_t)ROWS * NHEADS * 4);
    float* dAb  = (float*)alloc((size_t)ROWS * NHEADS * 4);
    float* ybuf = (float*)alloc((size_t)ROWS * DINNER * 4);
    __hip_bfloat16* gbf = (__hip_bfloat16*)xbuf;  // reuse: xbuf dead after scan

    cvt_bf16_kernel<<<(ROWS * DMODEL / 4 + 255) / 256, 256, 0, stream>>>(u, ubf, ROWS * DMODEL);
    padw1_kernel<<<(NPAD1 * DMODEL + 255) / 256, 256, 0, stream>>>(W_in, W1bf);
    cvt_bf16_kernel<<<(DMODEL * DINNER / 4 + 255) / 256, 256, 0, stream>>>(W_out, W2bf, DMODEL * DINNER);

    gemm_bf16_nt<<<dim3(ROWS / 128, (DINPROJ + 127) / 128), 256, 0, stream>>>(
        ubf, W1bf, zx, ROWS, DINPROJ, DMODEL, DINPROJ);

    conv_kernel<<<dim3((CONVDIM + 255) / 256, ROWS), 256, 0, stream>>>(
        zx, conv_w, conv_b, xbuf, Bmb, Cmb);

    dt_kernel<<<(ROWS * NHEADS + 255) / 256, 256, 0, stream>>>(zx, dt_bias, A_log, dtb, dAb);

    scan_kernel<<<BATCH * NHEADS * 8, 256, 0, stream>>>(xbuf, Bmb, Cmb, dtb, dAb, Dp, ybuf);

    gate_rms_kernel<<<ROWS, 256, 0, stream>>>(ybuf, zx, norm_w, gbf);

    gemm_bf16_nt<<<dim3(ROWS / 128, DMODEL / 128), 256, 0, stream>>>(
        gbf, W2bf, out, ROWS, DMODEL, DINNER, DMODEL);
}

// Round 2
// 1235.648 us; speedup vs baseline: 1.0001x; 1.0001x over previous
//
#include <hip/hip_runtime.h>
#include <hip/hip_bf16.h>
#include <stdint.h>

#define BATCH   2
#define SEQLEN  4096
#define DMODEL  768
#define DSTATE  64
#define DCONV   4
#define HEADDIM 128
#define NHEADS  12
#define DINNER  1536
#define DINPROJ 3212
#define CONVDIM 1664
#define NPAD1   3328            // 26*128, padded N for GEMM1 B-operand
#define ROWS    (BATCH*SEQLEN)  // 8192
#define CHUNK   64
#define NCHUNK  (SEQLEN/CHUNK)  // 64

typedef __bf16 bf16x8 __attribute__((ext_vector_type(8)));
typedef float  f32x4  __attribute__((ext_vector_type(4)));

__device__ __forceinline__ void load_lds16(const void* g, void* l) {
    __builtin_amdgcn_global_load_lds(
        (const __attribute__((address_space(1))) unsigned int*)g,
        (__attribute__((address_space(3))) unsigned int*)l, 16, 0, 0);
}

// ---------------- conversion kernels ----------------
__global__ void cvt_bf16_kernel(const float* __restrict__ src,
                                __hip_bfloat16* __restrict__ dst, int n) {
    int i = (blockIdx.x * blockDim.x + threadIdx.x) * 4;
    if (i + 3 < n) {
        float4 v = *(const float4*)(src + i);
        dst[i + 0] = __float2bfloat16(v.x);
        dst[i + 1] = __float2bfloat16(v.y);
        dst[i + 2] = __float2bfloat16(v.z);
        dst[i + 3] = __float2bfloat16(v.w);
    } else {
        for (; i < n; ++i) dst[i] = __float2bfloat16(src[i]);
    }
}

__global__ void padw1_kernel(const float* __restrict__ src,
                             __hip_bfloat16* __restrict__ dst) {
    int i = blockIdx.x * blockDim.x + threadIdx.x;
    if (i >= NPAD1 * DMODEL) return;
    int r = i / DMODEL;
    float v = (r < DINPROJ) ? src[i] : 0.f;
    dst[i] = __float2bfloat16(v);
}

// ---------------- bf16 MFMA GEMM: C = A(MxK) * Bt(NxK)^T  (m97 structure) ----
__global__ __launch_bounds__(256) void gemm_bf16_nt(
    const __hip_bfloat16* __restrict__ A,
    const __hip_bfloat16* __restrict__ Bt,
    float* __restrict__ C,
    int M, int Nreal, int K, int ldc)
{
    __shared__ __align__(16) __hip_bfloat16 As[128 * 32];
    __shared__ __align__(16) __hip_bfloat16 Bs[128 * 32];
    const int tid  = threadIdx.x;
    const int lane = tid & 63;
    const int wave = tid >> 6;
    const int wm   = wave >> 1;
    const int wn   = wave & 1;
    const int tm   = blockIdx.x * 128;
    const int tn   = blockIdx.y * 128;

    f32x4 acc[4][4] = {};

    const int lrow = tid >> 2;
    const int lk8  = (tid & 3) * 8;
    const __hip_bfloat16* gA0 = A  + (size_t)(tm + lrow)      * K + lk8;
    const __hip_bfloat16* gA1 = A  + (size_t)(tm + lrow + 64) * K + lk8;
    const __hip_bfloat16* gB0 = Bt + (size_t)(tn + lrow)      * K + lk8;
    const __hip_bfloat16* gB1 = Bt + (size_t)(tn + lrow + 64) * K + lk8;
    __hip_bfloat16* sA0 = As + tid * 8;
    __hip_bfloat16* sA1 = As + tid * 8 + 2048;
    __hip_bfloat16* sB0 = Bs + tid * 8;
    __hip_bfloat16* sB1 = Bs + tid * 8 + 2048;

    const int fr = lane & 15;
    const int fk = (lane >> 4) * 8;

    for (int kk = 0; kk < K; kk += 32) {
        load_lds16(gA0 + kk, sA0);
        load_lds16(gA1 + kk, sA1);
        load_lds16(gB0 + kk, sB0);
        load_lds16(gB1 + kk, sB1);
        __syncthreads();
        bf16x8 af[4], bfr[4];
#pragma unroll
        for (int i = 0; i < 4; ++i) {
            af[i]  = *(const bf16x8*)(As + (wm * 64 + i * 16 + fr) * 32 + fk);
            bfr[i] = *(const bf16x8*)(Bs + (wn * 64 + i * 16 + fr) * 32 + fk);
        }
#pragma unroll
        for (int mi = 0; mi < 4; ++mi)
#pragma unroll
            for (int ni = 0; ni < 4; ++ni)
                acc[mi][ni] = __builtin_amdgcn_mfma_f32_16x16x32_bf16(
                    af[mi], bfr[ni], acc[mi][ni], 0, 0, 0);
        __syncthreads();
    }

    const int rq = (lane >> 4) * 4;
#pragma unroll
    for (int mi = 0; mi < 4; ++mi) {
#pragma unroll
        for (int ni = 0; ni < 4; ++ni) {
            int col = tn + wn * 64 + ni * 16 + fr;
            if (col < Nreal) {
                size_t rbase = (size_t)(tm + wm * 64 + mi * 16 + rq) * ldc + col;
#pragma unroll
                for (int j = 0; j < 4; ++j)
                    C[rbase + (size_t)j * ldc] = acc[mi][ni][j];
            }
        }
    }
}

// ---------------- depthwise causal conv (D_CONV=4) + SiLU + split -----------
__global__ void conv_kernel(const float* __restrict__ zx,
                            const float* __restrict__ convw,
                            const float* __restrict__ convb,
                            float* __restrict__ xbuf,
                            float* __restrict__ Bm,
                            float* __restrict__ Cm)
{
    int c = blockIdx.x * 256 + threadIdx.x;
    if (c >= CONVDIM) return;
    int row = blockIdx.y;
    int l = row & (SEQLEN - 1);
    float acc = convb[c];
#pragma unroll
    for (int k = 0; k < 4; ++k) {
        int lt = l - 3 + k;
        if (lt >= 0)
            acc += zx[(size_t)(row - 3 + k) * DINPROJ + DINNER + c] * convw[c * 4 + k];
    }
    float v = acc / (1.f + expf(-acc));
    if (c < DINNER)               xbuf[(size_t)row * DINNER + c] = v;
    else if (c < DINNER + DSTATE) Bm[(size_t)row * DSTATE + (c - DINNER)] = v;
    else                          Cm[(size_t)row * DSTATE + (c - DINNER - DSTATE)] = v;
}

// ---------------- dt softplus + dA ----------------
__global__ void dt_kernel(const float* __restrict__ zx,
                          const float* __restrict__ dt_bias,
                          const float* __restrict__ A_log,
                          float* __restrict__ dtb, float* __restrict__ dAb)
{
    int i = blockIdx.x * 256 + threadIdx.x;
    if (i >= ROWS * NHEADS) return;
    int row = i / NHEADS, h = i - row * NHEADS;
    float v = zx[(size_t)row * DINPROJ + DINNER + CONVDIM + h] + dt_bias[h];
    float dt = (v > 20.f) ? v : log1pf(expf(v));
    float A = -expf(A_log[h]);
    dtb[i] = dt;
    dAb[i] = expf(dt * A);
}

// ---------------- chunk decay products: P[k] = prod dA over chunk ----------
__global__ void chunkdecay_kernel(const float* __restrict__ dAb,
                                  float* __restrict__ Pk)
{
    int i = blockIdx.x * 256 + threadIdx.x;   // (b*H+h)*NCHUNK + k
    if (i >= BATCH * NHEADS * NCHUNK) return;
    int k  = i % NCHUNK;
    int bh = i / NCHUNK;
    int h  = bh % NHEADS, b = bh / NHEADS;
    const float* base = dAb + ((size_t)(b * SEQLEN + k * CHUNK)) * NHEADS + h;
    float p = 1.f;
#pragma unroll 8
    for (int t = 0; t < CHUNK; ++t) p *= base[(size_t)t * NHEADS];
    Pk[i] = p;
}

// ---------------- scan phase 1: local chunk scan -> final local state ------
// blk = ((b*H+h)*NCHUNK + k)*8 + ps ; thread owns (p0+pl, n0..n0+3)
__global__ __launch_bounds__(256) void scan_phase1(
    const float* __restrict__ xbuf, const float* __restrict__ Bm,
    const float* __restrict__ dtb, const float* __restrict__ dAb,
    float* __restrict__ Sloc)
{
    int blk = blockIdx.x;
    int ps  = blk & 7;
    int k   = (blk >> 3) % NCHUNK;
    int bh  = (blk >> 3) / NCHUNK;
    int h   = bh % NHEADS;
    int b   = bh / NHEADS;
    int p0  = ps * 16;
    int tid = threadIdx.x;
    int pl  = tid >> 4;
    int n0  = (tid & 15) * 4;

    __shared__ __align__(16) float lB[CHUNK][64];
    __shared__ __align__(16) float lDtx[CHUNK][16];
    __shared__ float lDA[CHUNK];

    size_t row0 = (size_t)b * SEQLEN + k * CHUNK;
    for (int i = tid; i < CHUNK * 64 / 4; i += 256)
        ((float4*)&lB[0][0])[i] = ((const float4*)Bm)[row0 * 16 + i];
    for (int i = tid; i < CHUNK * 16; i += 256) {
        int t = i >> 4, pp = i & 15;
        size_t r = row0 + t;
        lDtx[t][pp] = dtb[r * NHEADS + h] * xbuf[(r * NHEADS + h) * HEADDIM + p0 + pp];
    }
    if (tid < CHUNK) lDA[tid] = dAb[(row0 + tid) * NHEADS + h];
    __syncthreads();

    float s0 = 0.f, s1 = 0.f, s2 = 0.f, s3 = 0.f;
#pragma unroll 8
    for (int t = 0; t < CHUNK; ++t) {
        float da  = lDA[t];
        float dtx = lDtx[t][pl];
        const float* bp = &lB[t][n0];
        s0 = s0 * da + dtx * bp[0];
        s1 = s1 * da + dtx * bp[1];
        s2 = s2 * da + dtx * bp[2];
        s3 = s3 * da + dtx * bp[3];
    }
    f32x4 sv = {s0, s1, s2, s3};
    size_t si = ((size_t)(bh * NCHUNK + k) * HEADDIM + (p0 + pl)) * DSTATE + n0;
    *(f32x4*)(Sloc + si) = sv;
}

// ---------------- scan phase 2: inter-chunk prefix (in-place F -> S_init) --
__global__ __launch_bounds__(256) void scan_phase2(
    float* __restrict__ Sloc, const float* __restrict__ Pk)
{
    int bh = blockIdx.x >> 5;                       // 32 blocks per (b,h)
    int eo = (blockIdx.x & 31) * 256 + threadIdx.x; // 0..8191
    __shared__ float lP[NCHUNK];
    if (threadIdx.x < NCHUNK) lP[threadIdx.x] = Pk[bh * NCHUNK + threadIdx.x];
    __syncthreads();
    float s = 0.f;
    size_t base = (size_t)bh * NCHUNK * 8192 + eo;
#pragma unroll 8
    for (int k = 0; k < NCHUNK; ++k) {
        size_t a = base + (size_t)k * 8192;
        float f = Sloc[a];
        Sloc[a] = s;               // S_init[k] = state before chunk k
        s = s * lP[k] + f;
    }
}

// ---------------- scan phase 3: re-scan chunk from S_init, emit y ----------
__global__ __launch_bounds__(256) void scan_phase3(
    const float* __restrict__ xbuf, const float* __restrict__ Bm,
    const float* __restrict__ Cm, const float* __restrict__ dtb,
    const float* __restrict__ dAb, const float* __restrict__ Dp,
    const float* __restrict__ Sini, float* __restrict__ ybuf)
{
    int blk = blockIdx.x;
    int ps  = blk & 7;
    int k   = (blk >> 3) % NCHUNK;
    int bh  = (blk >> 3) / NCHUNK;
    int h   = bh % NHEADS;
    int b   = bh / NHEADS;
    int p0  = ps * 16;
    int tid = threadIdx.x;
    int pl  = tid >> 4;
    int n0  = (tid & 15) * 4;

    __shared__ __align__(16) float lB[CHUNK][64];
    __shared__ __align__(16) float lC[CHUNK][64];
    __shared__ __align__(16) float lDtx[CHUNK][16];
    __shared__ float lDA[CHUNK];
    __shared__ float lY[CHUNK][16];

    size_t row0 = (size_t)b * SEQLEN + k * CHUNK;
    for (int i = tid; i < CHUNK * 64 / 4; i += 256) {
        ((float4*)&lB[0][0])[i] = ((const float4*)Bm)[row0 * 16 + i];
        ((float4*)&lC[0][0])[i] = ((const float4*)Cm)[row0 * 16 + i];
    }
    for (int i = tid; i < CHUNK * 16; i += 256) {
        int t = i >> 4, pp = i & 15;
        size_t r = row0 + t;
        lDtx[t][pp] = dtb[r * NHEADS + h] * xbuf[(r * NHEADS + h) * HEADDIM + p0 + pp];
    }
    if (tid < CHUNK) lDA[tid] = dAb[(row0 + tid) * NHEADS + h];

    size_t si = ((size_t)(bh * NCHUNK + k) * HEADDIM + (p0 + pl)) * DSTATE + n0;
    f32x4 sv = *(const f32x4*)(Sini + si);
    float s0 = sv[0], s1 = sv[1], s2 = sv[2], s3 = sv[3];
    __syncthreads();

    for (int t = 0; t < CHUNK; ++t) {
        float da  = lDA[t];
        float dtx = lDtx[t][pl];
        const float* bp = &lB[t][n0];
        const float* cp = &lC[t][n0];
        s0 = s0 * da + dtx * bp[0];
        s1 = s1 * da + dtx * bp[1];
        s2 = s2 * da + dtx * bp[2];
        s3 = s3 * da + dtx * bp[3];
        float part = s0 * cp[0] + s1 * cp[1] + s2 * cp[2] + s3 * cp[3];
        part += __shfl_xor(part, 1);
        part += __shfl_xor(part, 2);
        part += __shfl_xor(part, 4);
        part += __shfl_xor(part, 8);
        if ((tid & 15) == 0) lY[t][pl] = part;
    }
    __syncthreads();

    float dph = Dp[h];
    for (int i = tid; i < CHUNK * 16; i += 256) {
        int t = i >> 4, pp = i & 15;
        size_t r = row0 + t;
        size_t gi = (r * NHEADS + h) * HEADDIM + p0 + pp;
        ybuf[gi] = lY[t][pp] + dph * xbuf[gi];
    }
}

// ---------------- fallback: original monolithic scan ------------------------
#define NT 64
__global__ __launch_bounds__(256) void scan_kernel(
    const float* __restrict__ xbuf, const float* __restrict__ Bm,
    const float* __restrict__ Cm, const float* __restrict__ dtb,
    const float* __restrict__ dAb, const float* __restrict__ Dp,
    float* __restrict__ ybuf)
{
    int blk = blockIdx.x;
    int ps = blk & 7;
    int h  = (blk >> 3) % NHEADS;
    int b  = blk / (NHEADS * 8);
    int p0 = ps * 16;
    int tid = threadIdx.x;
    int pl  = tid >> 4;
    int n0  = (tid & 15) * 4;

    __shared__ __align__(16) float lB[NT][64];
    __shared__ __align__(16) float lC[NT][64];
    __shared__ __align__(16) float lDtx[NT][16];
    __shared__ float lDA[NT];
    __shared__ float lY[NT][16];

    float s0 = 0.f, s1 = 0.f, s2 = 0.f, s3 = 0.f;
    float dph = Dp[h];
    size_t rowbase = (size_t)b * SEQLEN;

    for (int t0 = 0; t0 < SEQLEN; t0 += NT) {
        for (int i = tid; i < NT * 64 / 4; i += 256) {
            ((float4*)&lB[0][0])[i] = ((const float4*)Bm)[(rowbase + t0) * 16 + i];
            ((float4*)&lC[0][0])[i] = ((const float4*)Cm)[(rowbase + t0) * 16 + i];
        }
        for (int i = tid; i < NT * 16; i += 256) {
            int t = i >> 4, pp = i & 15;
            size_t r = rowbase + t0 + t;
            lDtx[t][pp] = dtb[r * NHEADS + h] * xbuf[(r * NHEADS + h) * HEADDIM + p0 + pp];
        }
        if (tid < NT) lDA[tid] = dAb[(rowbase + t0 + tid) * NHEADS + h];
        __syncthreads();

        for (int t = 0; t < NT; ++t) {
            float da  = lDA[t];
            float dtx = lDtx[t][pl];
            const float* bp = &lB[t][n0];
            const float* cp = &lC[t][n0];
            s0 = s0 * da + dtx * bp[0];
            s1 = s1 * da + dtx * bp[1];
            s2 = s2 * da + dtx * bp[2];
            s3 = s3 * da + dtx * bp[3];
            float part = s0 * cp[0] + s1 * cp[1] + s2 * cp[2] + s3 * cp[3];
            part += __shfl_xor(part, 1);
            part += __shfl_xor(part, 2);
            part += __shfl_xor(part, 4);
            part += __shfl_xor(part, 8);
            if ((tid & 15) == 0) lY[t][pl] = part;
        }
        __syncthreads();

        for (int i = tid; i < NT * 16; i += 256) {
            int t = i >> 4, pp = i & 15;
            size_t r = rowbase + t0 + t;
            size_t gi = (r * NHEADS + h) * HEADDIM + p0 + pp;
            ybuf[gi] = lY[t][pp] + dph * xbuf[gi];
        }
        __syncthreads();
    }
}

// ---------------- gate (y * silu(z)) + RMSNorm -> bf16 ----------------------
__global__ __launch_bounds__(256) void gate_rms_kernel(
    const float* __restrict__ ybuf, const float* __restrict__ zx,
    const float* __restrict__ norm_w, __hip_bfloat16* __restrict__ gbf)
{
    int row = blockIdx.x;
    int tid = threadIdx.x;
    const float* y = ybuf + (size_t)row * DINNER;
    const float* z = zx + (size_t)row * DINPROJ;
    float g[6];
    float ss = 0.f;
#pragma unroll
    for (int j = 0; j < 6; ++j) {
        int idx = tid + j * 256;
        float zz = z[idx];
        float gv = y[idx] * (zz / (1.f + expf(-zz)));
        g[j] = gv;
        ss += gv * gv;
    }
#pragma unroll
    for (int m = 1; m < 64; m <<= 1) ss += __shfl_xor(ss, m);
    __shared__ float red[4];
    if ((tid & 63) == 0) red[tid >> 6] = ss;
    __syncthreads();
    float tot = red[0] + red[1] + red[2] + red[3];
    float scale = rsqrtf(tot * (1.f / DINNER) + 1e-5f);
#pragma unroll
    for (int j = 0; j < 6; ++j) {
        int idx = tid + j * 256;
        gbf[(size_t)row * DINNER + idx] = __float2bfloat16(g[j] * scale * norm_w[idx]);
    }
}

// ---------------- launch ----------------
extern "C" void kernel_launch(void* const* d_in, const int* in_sizes, int n_in,
                              void* d_out, int out_size, void* d_ws, size_t ws_size,
                              hipStream_t stream)
{
    const float* u       = (const float*)d_in[0];
    const float* W_in    = (const float*)d_in[1];
    const float* conv_w  = (const float*)d_in[2];
    const float* conv_b  = (const float*)d_in[3];
    const float* dt_bias = (const float*)d_in[4];
    const float* A_log   = (const float*)d_in[5];
    const float* Dp      = (const float*)d_in[6];
    const float* norm_w  = (const float*)d_in[7];
    const float* W_out   = (const float*)d_in[8];
    float* out = (float*)d_out;

    char* ws = (char*)d_ws;
    size_t off = 0;
    auto alloc = [&](size_t bytes) {
        char* p = ws + off;
        off += (bytes + 255) & ~(size_t)255;
        return p;
    };
    __hip_bfloat16* ubf  = (__hip_bfloat16*)alloc((size_t)ROWS * DMODEL * 2);
    __hip_bfloat16* W1bf = (__hip_bfloat16*)alloc((size_t)NPAD1 * DMODEL * 2);
    __hip_bfloat16* W2bf = (__hip_bfloat16*)alloc((size_t)DMODEL * DINNER * 2);
    float* zx   = (float*)alloc((size_t)ROWS * DINPROJ * 4);
    float* xbuf = (float*)alloc((size_t)ROWS * DINNER * 4);
    float* Bmb  = (float*)alloc((size_t)ROWS * DSTATE * 4);
    float* Cmb  = (float*)alloc((size_t)ROWS * DSTATE * 4);
    float* dtb  = (float*)alloc((size_t)ROWS * NHEADS * 4);
    float* dAb  = (float*)alloc((size_t)ROWS * NHEADS * 4);
    float* ybuf = (float*)alloc((size_t)ROWS * DINNER * 4);
    __hip_bfloat16* gbf = (__hip_bfloat16*)xbuf;  // reuse: xbuf dead after scan

    // chunked-scan extra buffers (used only if ws is large enough)
    float* Sloc = (float*)alloc((size_t)BATCH * NHEADS * NCHUNK * HEADDIM * DSTATE * 4);
    float* Pkb  = (float*)alloc((size_t)BATCH * NHEADS * NCHUNK * 4);
    bool chunked = (off <= ws_size);

    cvt_bf16_kernel<<<(ROWS * DMODEL / 4 + 255) / 256, 256, 0, stream>>>(u, ubf, ROWS * DMODEL);
    padw1_kernel<<<(NPAD1 * DMODEL + 255) / 256, 256, 0, stream>>>(W_in, W1bf);
    cvt_bf16_kernel<<<(DMODEL * DINNER / 4 + 255) / 256, 256, 0, stream>>>(W_out, W2bf, DMODEL * DINNER);

    gemm_bf16_nt<<<dim3(ROWS / 128, (DINPROJ + 127) / 128), 256, 0, stream>>>(
        ubf, W1bf, zx, ROWS, DINPROJ, DMODEL, DINPROJ);

    conv_kernel<<<dim3((CONVDIM + 255) / 256, ROWS), 256, 0, stream>>>(
        zx, conv_w, conv_b, xbuf, Bmb, Cmb);

    dt_kernel<<<(ROWS * NHEADS + 255) / 256, 256, 0, stream>>>(zx, dt_bias, A_log, dtb, dAb);

    if (chunked) {
        chunkdecay_kernel<<<(BATCH * NHEADS * NCHUNK + 255) / 256, 256, 0, stream>>>(dAb, Pkb);
        scan_phase1<<<BATCH * NHEADS * NCHUNK * 8, 256, 0, stream>>>(
            xbuf, Bmb, dtb, dAb, Sloc);
        scan_phase2<<<BATCH * NHEADS * 32, 256, 0, stream>>>(Sloc, Pkb);
        scan_phase3<<<BATCH * NHEADS * NCHUNK * 8, 256, 0, stream>>>(
            xbuf, Bmb, Cmb, dtb, dAb, Dp, Sloc, ybuf);
    } else {
        scan_kernel<<<BATCH * NHEADS * 8, 256, 0, stream>>>(
            xbuf, Bmb, Cmb, dtb, dAb, Dp, ybuf);
    }

    gate_rms_kernel<<<ROWS, 256, 0, stream>>>(ybuf, zx, norm_w, gbf);

    gemm_bf16_nt<<<dim3(ROWS / 128, DMODEL / 128), 256, 0, stream>>>(
        gbf, W2bf, out, ROWS, DMODEL, DINNER, DMODEL);
}

// Round 3
// 606.843 us; speedup vs baseline: 2.0363x; 2.0362x over previous
//
#include <hip/hip_runtime.h>
#include <hip/hip_bf16.h>
#include <stdint.h>

#define BATCH   2
#define SEQLEN  4096
#define DMODEL  768
#define DSTATE  64
#define DCONV   4
#define HEADDIM 128
#define NHEADS  12
#define DINNER  1536
#define DINPROJ 3212
#define CONVDIM 1664
#define DXBC    1676            // CONVDIM + NHEADS (xBC + dt columns)
#define NPAD1   3328            // 26*128, padded rows of W_in (bf16 copy)
#define ROWS    (BATCH*SEQLEN)  // 8192
#define CHUNK   64
#define NCHUNK  (SEQLEN/CHUNK)  // 64

typedef __bf16 bf16x8 __attribute__((ext_vector_type(8)));
typedef float  f32x4  __attribute__((ext_vector_type(4)));

__device__ __forceinline__ void load_lds16(const void* g, void* l) {
    __builtin_amdgcn_global_load_lds(
        (const __attribute__((address_space(1))) unsigned int*)g,
        (__attribute__((address_space(3))) unsigned int*)l, 16, 0, 0);
}

// ---------------- conversion kernels ----------------
__global__ void cvt_bf16_kernel(const float* __restrict__ src,
                                __hip_bfloat16* __restrict__ dst, int n) {
    int i = (blockIdx.x * blockDim.x + threadIdx.x) * 4;
    if (i + 3 < n) {
        float4 v = *(const float4*)(src + i);
        dst[i + 0] = __float2bfloat16(v.x);
        dst[i + 1] = __float2bfloat16(v.y);
        dst[i + 2] = __float2bfloat16(v.z);
        dst[i + 3] = __float2bfloat16(v.w);
    } else {
        for (; i < n; ++i) dst[i] = __float2bfloat16(src[i]);
    }
}

__global__ void padw1_kernel(const float* __restrict__ src,
                             __hip_bfloat16* __restrict__ dst) {
    int i = blockIdx.x * blockDim.x + threadIdx.x;
    if (i >= NPAD1 * DMODEL) return;
    int r = i / DMODEL;
    float v = (r < DINPROJ) ? src[i] : 0.f;
    dst[i] = __float2bfloat16(v);
}

// ---------------- bf16 MFMA GEMM: C = A(MxK) * Bt(NxK)^T  (m97 structure) ----
__global__ __launch_bounds__(256) void gemm_bf16_nt(
    const __hip_bfloat16* __restrict__ A,
    const __hip_bfloat16* __restrict__ Bt,
    float* __restrict__ C,
    int M, int Nreal, int K, int ldc)
{
    __shared__ __align__(16) __hip_bfloat16 As[128 * 32];
    __shared__ __align__(16) __hip_bfloat16 Bs[128 * 32];
    const int tid  = threadIdx.x;
    const int lane = tid & 63;
    const int wave = tid >> 6;
    const int wm   = wave >> 1;
    const int wn   = wave & 1;
    const int tm   = blockIdx.x * 128;
    const int tn   = blockIdx.y * 128;

    f32x4 acc[4][4] = {};

    const int lrow = tid >> 2;
    const int lk8  = (tid & 3) * 8;
    const __hip_bfloat16* gA0 = A  + (size_t)(tm + lrow)      * K + lk8;
    const __hip_bfloat16* gA1 = A  + (size_t)(tm + lrow + 64) * K + lk8;
    const __hip_bfloat16* gB0 = Bt + (size_t)(tn + lrow)      * K + lk8;
    const __hip_bfloat16* gB1 = Bt + (size_t)(tn + lrow + 64) * K + lk8;
    __hip_bfloat16* sA0 = As + tid * 8;
    __hip_bfloat16* sA1 = As + tid * 8 + 2048;
    __hip_bfloat16* sB0 = Bs + tid * 8;
    __hip_bfloat16* sB1 = Bs + tid * 8 + 2048;

    const int fr = lane & 15;
    const int fk = (lane >> 4) * 8;

    for (int kk = 0; kk < K; kk += 32) {
        load_lds16(gA0 + kk, sA0);
        load_lds16(gA1 + kk, sA1);
        load_lds16(gB0 + kk, sB0);
        load_lds16(gB1 + kk, sB1);
        __syncthreads();
        bf16x8 af[4], bfr[4];
#pragma unroll
        for (int i = 0; i < 4; ++i) {
            af[i]  = *(const bf16x8*)(As + (wm * 64 + i * 16 + fr) * 32 + fk);
            bfr[i] = *(const bf16x8*)(Bs + (wn * 64 + i * 16 + fr) * 32 + fk);
        }
#pragma unroll
        for (int mi = 0; mi < 4; ++mi)
#pragma unroll
            for (int ni = 0; ni < 4; ++ni)
                acc[mi][ni] = __builtin_amdgcn_mfma_f32_16x16x32_bf16(
                    af[mi], bfr[ni], acc[mi][ni], 0, 0, 0);
        __syncthreads();
    }

    const int rq = (lane >> 4) * 4;
#pragma unroll
    for (int mi = 0; mi < 4; ++mi) {
#pragma unroll
        for (int ni = 0; ni < 4; ++ni) {
            int col = tn + wn * 64 + ni * 16 + fr;
            if (col < Nreal) {
                size_t rbase = (size_t)(tm + wm * 64 + mi * 16 + rq) * ldc + col;
#pragma unroll
                for (int j = 0; j < 4; ++j)
                    C[rbase + (size_t)j * ldc] = acc[mi][ni][j];
            }
        }
    }
}

// ---------------- depthwise causal conv (D_CONV=4) + SiLU + split -----------
__global__ void conv_kernel(const float* __restrict__ xbcdt,
                            const float* __restrict__ convw,
                            const float* __restrict__ convb,
                            float* __restrict__ xbuf,
                            float* __restrict__ Bm,
                            float* __restrict__ Cm)
{
    int c = blockIdx.x * 256 + threadIdx.x;
    if (c >= CONVDIM) return;
    int row = blockIdx.y;
    int l = row & (SEQLEN - 1);
    float acc = convb[c];
#pragma unroll
    for (int k = 0; k < 4; ++k) {
        int lt = l - 3 + k;
        if (lt >= 0)
            acc += xbcdt[(size_t)(row - 3 + k) * DXBC + c] * convw[c * 4 + k];
    }
    float v = acc / (1.f + expf(-acc));
    if (c < DINNER)               xbuf[(size_t)row * DINNER + c] = v;
    else if (c < DINNER + DSTATE) Bm[(size_t)row * DSTATE + (c - DINNER)] = v;
    else                          Cm[(size_t)row * DSTATE + (c - DINNER - DSTATE)] = v;
}

// ---------------- dt softplus + dA ----------------
__global__ void dt_kernel(const float* __restrict__ xbcdt,
                          const float* __restrict__ dt_bias,
                          const float* __restrict__ A_log,
                          float* __restrict__ dtb, float* __restrict__ dAb)
{
    int i = blockIdx.x * 256 + threadIdx.x;
    if (i >= ROWS * NHEADS) return;
    int row = i / NHEADS, h = i - row * NHEADS;
    float v = xbcdt[(size_t)row * DXBC + CONVDIM + h] + dt_bias[h];
    float dt = (v > 20.f) ? v : log1pf(expf(v));
    float A = -expf(A_log[h]);
    dtb[i] = dt;
    dAb[i] = expf(dt * A);
}

// ---------------- chunk decay products: P[k] = prod dA over chunk ----------
__global__ void chunkdecay_kernel(const float* __restrict__ dAb,
                                  float* __restrict__ Pk)
{
    int i = blockIdx.x * 256 + threadIdx.x;   // (b*H+h)*NCHUNK + k
    if (i >= BATCH * NHEADS * NCHUNK) return;
    int k  = i % NCHUNK;
    int bh = i / NCHUNK;
    int h  = bh % NHEADS, b = bh / NHEADS;
    const float* base = dAb + ((size_t)(b * SEQLEN + k * CHUNK)) * NHEADS + h;
    float p = 1.f;
#pragma unroll 8
    for (int t = 0; t < CHUNK; ++t) p *= base[(size_t)t * NHEADS];
    Pk[i] = p;
}

// ---------------- scan phase 1: local chunk scan -> final local state ------
// blk = ((b*H+h)*NCHUNK + k)*8 + ps ; thread owns (p0+pl, n0..n0+3)
__global__ __launch_bounds__(256) void scan_phase1(
    const float* __restrict__ xbuf, const float* __restrict__ Bm,
    const float* __restrict__ dtb, const float* __restrict__ dAb,
    float* __restrict__ Sloc)
{
    int blk = blockIdx.x;
    int ps  = blk & 7;
    int k   = (blk >> 3) % NCHUNK;
    int bh  = (blk >> 3) / NCHUNK;
    int h   = bh % NHEADS;
    int b   = bh / NHEADS;
    int p0  = ps * 16;
    int tid = threadIdx.x;
    int pl  = tid >> 4;
    int n0  = (tid & 15) * 4;

    __shared__ __align__(16) float lB[CHUNK][64];
    __shared__ __align__(16) float lDtx[CHUNK][16];
    __shared__ float lDA[CHUNK];

    size_t row0 = (size_t)b * SEQLEN + k * CHUNK;
    for (int i = tid; i < CHUNK * 64 / 4; i += 256)
        ((float4*)&lB[0][0])[i] = ((const float4*)Bm)[row0 * 16 + i];
    for (int i = tid; i < CHUNK * 16; i += 256) {
        int t = i >> 4, pp = i & 15;
        size_t r = row0 + t;
        lDtx[t][pp] = dtb[r * NHEADS + h] * xbuf[(r * NHEADS + h) * HEADDIM + p0 + pp];
    }
    if (tid < CHUNK) lDA[tid] = dAb[(row0 + tid) * NHEADS + h];
    __syncthreads();

    float s0 = 0.f, s1 = 0.f, s2 = 0.f, s3 = 0.f;
#pragma unroll 8
    for (int t = 0; t < CHUNK; ++t) {
        float da  = lDA[t];
        float dtx = lDtx[t][pl];
        const float* bp = &lB[t][n0];
        s0 = s0 * da + dtx * bp[0];
        s1 = s1 * da + dtx * bp[1];
        s2 = s2 * da + dtx * bp[2];
        s3 = s3 * da + dtx * bp[3];
    }
    f32x4 sv = {s0, s1, s2, s3};
    size_t si = ((size_t)(bh * NCHUNK + k) * HEADDIM + (p0 + pl)) * DSTATE + n0;
    *(f32x4*)(Sloc + si) = sv;
}

// ---------------- scan phase 2: inter-chunk prefix (in-place F -> S_init) --
__global__ __launch_bounds__(256) void scan_phase2(
    float* __restrict__ Sloc, const float* __restrict__ Pk)
{
    int bh = blockIdx.x >> 5;                       // 32 blocks per (b,h)
    int eo = (blockIdx.x & 31) * 256 + threadIdx.x; // 0..8191
    __shared__ float lP[NCHUNK];
    if (threadIdx.x < NCHUNK) lP[threadIdx.x] = Pk[bh * NCHUNK + threadIdx.x];
    __syncthreads();
    float s = 0.f;
    size_t base = (size_t)bh * NCHUNK * 8192 + eo;
#pragma unroll 8
    for (int k = 0; k < NCHUNK; ++k) {
        size_t a = base + (size_t)k * 8192;
        float f = Sloc[a];
        Sloc[a] = s;               // S_init[k] = state before chunk k
        s = s * lP[k] + f;
    }
}

// ---------------- scan phase 3: re-scan chunk from S_init, emit y ----------
__global__ __launch_bounds__(256) void scan_phase3(
    const float* __restrict__ xbuf, const float* __restrict__ Bm,
    const float* __restrict__ Cm, const float* __restrict__ dtb,
    const float* __restrict__ dAb, const float* __restrict__ Dp,
    const float* __restrict__ Sini, float* __restrict__ ybuf)
{
    int blk = blockIdx.x;
    int ps  = blk & 7;
    int k   = (blk >> 3) % NCHUNK;
    int bh  = (blk >> 3) / NCHUNK;
    int h   = bh % NHEADS;
    int b   = bh / NHEADS;
    int p0  = ps * 16;
    int tid = threadIdx.x;
    int pl  = tid >> 4;
    int n0  = (tid & 15) * 4;

    __shared__ __align__(16) float lB[CHUNK][64];
    __shared__ __align__(16) float lC[CHUNK][64];
    __shared__ __align__(16) float lDtx[CHUNK][16];
    __shared__ float lDA[CHUNK];
    __shared__ float lY[CHUNK][16];

    size_t row0 = (size_t)b * SEQLEN + k * CHUNK;
    for (int i = tid; i < CHUNK * 64 / 4; i += 256) {
        ((float4*)&lB[0][0])[i] = ((const float4*)Bm)[row0 * 16 + i];
        ((float4*)&lC[0][0])[i] = ((const float4*)Cm)[row0 * 16 + i];
    }
    for (int i = tid; i < CHUNK * 16; i += 256) {
        int t = i >> 4, pp = i & 15;
        size_t r = row0 + t;
        lDtx[t][pp] = dtb[r * NHEADS + h] * xbuf[(r * NHEADS + h) * HEADDIM + p0 + pp];
    }
    if (tid < CHUNK) lDA[tid] = dAb[(row0 + tid) * NHEADS + h];

    size_t si = ((size_t)(bh * NCHUNK + k) * HEADDIM + (p0 + pl)) * DSTATE + n0;
    f32x4 sv = *(const f32x4*)(Sini + si);
    float s0 = sv[0], s1 = sv[1], s2 = sv[2], s3 = sv[3];
    __syncthreads();

    for (int t = 0; t < CHUNK; ++t) {
        float da  = lDA[t];
        float dtx = lDtx[t][pl];
        const float* bp = &lB[t][n0];
        const float* cp = &lC[t][n0];
        s0 = s0 * da + dtx * bp[0];
        s1 = s1 * da + dtx * bp[1];
        s2 = s2 * da + dtx * bp[2];
        s3 = s3 * da + dtx * bp[3];
        float part = s0 * cp[0] + s1 * cp[1] + s2 * cp[2] + s3 * cp[3];
        part += __shfl_xor(part, 1);
        part += __shfl_xor(part, 2);
        part += __shfl_xor(part, 4);
        part += __shfl_xor(part, 8);
        if ((tid & 15) == 0) lY[t][pl] = part;
    }
    __syncthreads();

    float dph = Dp[h];
    for (int i = tid; i < CHUNK * 16; i += 256) {
        int t = i >> 4, pp = i & 15;
        size_t r = row0 + t;
        size_t gi = (r * NHEADS + h) * HEADDIM + p0 + pp;
        ybuf[gi] = lY[t][pp] + dph * xbuf[gi];
    }
}

// ---------------- fallback: original monolithic scan ------------------------
#define NT 64
__global__ __launch_bounds__(256) void scan_kernel(
    const float* __restrict__ xbuf, const float* __restrict__ Bm,
    const float* __restrict__ Cm, const float* __restrict__ dtb,
    const float* __restrict__ dAb, const float* __restrict__ Dp,
    float* __restrict__ ybuf)
{
    int blk = blockIdx.x;
    int ps = blk & 7;
    int h  = (blk >> 3) % NHEADS;
    int b  = blk / (NHEADS * 8);
    int p0 = ps * 16;
    int tid = threadIdx.x;
    int pl  = tid >> 4;
    int n0  = (tid & 15) * 4;

    __shared__ __align__(16) float lB[NT][64];
    __shared__ __align__(16) float lC[NT][64];
    __shared__ __align__(16) float lDtx[NT][16];
    __shared__ float lDA[NT];
    __shared__ float lY[NT][16];

    float s0 = 0.f, s1 = 0.f, s2 = 0.f, s3 = 0.f;
    float dph = Dp[h];
    size_t rowbase = (size_t)b * SEQLEN;

    for (int t0 = 0; t0 < SEQLEN; t0 += NT) {
        for (int i = tid; i < NT * 64 / 4; i += 256) {
            ((float4*)&lB[0][0])[i] = ((const float4*)Bm)[(rowbase + t0) * 16 + i];
            ((float4*)&lC[0][0])[i] = ((const float4*)Cm)[(rowbase + t0) * 16 + i];
        }
        for (int i = tid; i < NT * 16; i += 256) {
            int t = i >> 4, pp = i & 15;
            size_t r = rowbase + t0 + t;
            lDtx[t][pp] = dtb[r * NHEADS + h] * xbuf[(r * NHEADS + h) * HEADDIM + p0 + pp];
        }
        if (tid < NT) lDA[tid] = dAb[(rowbase + t0 + tid) * NHEADS + h];
        __syncthreads();

        for (int t = 0; t < NT; ++t) {
            float da  = lDA[t];
            float dtx = lDtx[t][pl];
            const float* bp = &lB[t][n0];
            const float* cp = &lC[t][n0];
            s0 = s0 * da + dtx * bp[0];
            s1 = s1 * da + dtx * bp[1];
            s2 = s2 * da + dtx * bp[2];
            s3 = s3 * da + dtx * bp[3];
            float part = s0 * cp[0] + s1 * cp[1] + s2 * cp[2] + s3 * cp[3];
            part += __shfl_xor(part, 1);
            part += __shfl_xor(part, 2);
            part += __shfl_xor(part, 4);
            part += __shfl_xor(part, 8);
            if ((tid & 15) == 0) lY[t][pl] = part;
        }
        __syncthreads();

        for (int i = tid; i < NT * 16; i += 256) {
            int t = i >> 4, pp = i & 15;
            size_t r = rowbase + t0 + t;
            size_t gi = (r * NHEADS + h) * HEADDIM + p0 + pp;
            ybuf[gi] = lY[t][pp] + dph * xbuf[gi];
        }
        __syncthreads();
    }
}

// ---------------- gate (y * silu(z)) + RMSNorm -> bf16 ----------------------
__global__ __launch_bounds__(256) void gate_rms_kernel(
    const float* __restrict__ ybuf, const float* __restrict__ zbuf,
    const float* __restrict__ norm_w, __hip_bfloat16* __restrict__ gbf)
{
    int row = blockIdx.x;
    int tid = threadIdx.x;
    const float* y = ybuf + (size_t)row * DINNER;
    const float* z = zbuf + (size_t)row * DINNER;
    float g[6];
    float ss = 0.f;
#pragma unroll
    for (int j = 0; j < 6; ++j) {
        int idx = tid + j * 256;
        float zz = z[idx];
        float gv = y[idx] * (zz / (1.f + expf(-zz)));
        g[j] = gv;
        ss += gv * gv;
    }
#pragma unroll
    for (int m = 1; m < 64; m <<= 1) ss += __shfl_xor(ss, m);
    __shared__ float red[4];
    if ((tid & 63) == 0) red[tid >> 6] = ss;
    __syncthreads();
    float tot = red[0] + red[1] + red[2] + red[3];
    float scale = rsqrtf(tot * (1.f / DINNER) + 1e-5f);
#pragma unroll
    for (int j = 0; j < 6; ++j) {
        int idx = tid + j * 256;
        gbf[(size_t)row * DINNER + idx] = __float2bfloat16(g[j] * scale * norm_w[idx]);
    }
}

// ---------------- launch ----------------
extern "C" void kernel_launch(void* const* d_in, const int* in_sizes, int n_in,
                              void* d_out, int out_size, void* d_ws, size_t ws_size,
                              hipStream_t stream)
{
    const float* u       = (const float*)d_in[0];
    const float* W_in    = (const float*)d_in[1];
    const float* conv_w  = (const float*)d_in[2];
    const float* conv_b  = (const float*)d_in[3];
    const float* dt_bias = (const float*)d_in[4];
    const float* A_log   = (const float*)d_in[5];
    const float* Dp      = (const float*)d_in[6];
    const float* norm_w  = (const float*)d_in[7];
    const float* W_out   = (const float*)d_in[8];
    float* out = (float*)d_out;

    char* ws = (char*)d_ws;
    size_t off = 0;
    auto alloc = [&](size_t bytes) {
        char* p = ws + off;
        off += (bytes + 255) & ~(size_t)255;
        return p;
    };
    __hip_bfloat16* ubf  = (__hip_bfloat16*)alloc((size_t)ROWS * DMODEL * 2);
    __hip_bfloat16* W1bf = (__hip_bfloat16*)alloc((size_t)NPAD1 * DMODEL * 2);
    __hip_bfloat16* W2bf = (__hip_bfloat16*)alloc((size_t)DMODEL * DINNER * 2);
    float* zbuf  = (float*)alloc((size_t)ROWS * DINNER * 4);   // z columns
    float* xbcdt = (float*)alloc((size_t)ROWS * DXBC * 4);     // xBC + dt columns
    float* xbuf = (float*)alloc((size_t)ROWS * DINNER * 4);
    float* Bmb  = (float*)alloc((size_t)ROWS * DSTATE * 4);
    float* Cmb  = (float*)alloc((size_t)ROWS * DSTATE * 4);
    float* dtb  = (float*)alloc((size_t)ROWS * NHEADS * 4);
    float* dAb  = (float*)alloc((size_t)ROWS * NHEADS * 4);
    float* ybuf = (float*)alloc((size_t)ROWS * DINNER * 4);
    float* Pkb  = (float*)alloc((size_t)BATCH * NHEADS * NCHUNK * 4);
    __hip_bfloat16* gbf = (__hip_bfloat16*)xbuf;  // reuse: xbuf dead after scan
    // ALIAS: xbcdt (54.9 MB) is dead after conv_kernel + dt_kernel;
    // Sloc needs 50.3 MB -> reuse the same memory, no footprint growth.
    float* Sloc = (float*)xbcdt;
    bool chunked = (off <= ws_size);   // same footprint as round 1 -> should hold

    cvt_bf16_kernel<<<(ROWS * DMODEL / 4 + 255) / 256, 256, 0, stream>>>(u, ubf, ROWS * DMODEL);
    padw1_kernel<<<(NPAD1 * DMODEL + 255) / 256, 256, 0, stream>>>(W_in, W1bf);
    cvt_bf16_kernel<<<(DMODEL * DINNER / 4 + 255) / 256, 256, 0, stream>>>(W_out, W2bf, DMODEL * DINNER);

    // GEMM1 split: z columns (0..1535) and xBC+dt columns (1536..3211)
    gemm_bf16_nt<<<dim3(ROWS / 128, DINNER / 128), 256, 0, stream>>>(
        ubf, W1bf, zbuf, ROWS, DINNER, DMODEL, DINNER);
    gemm_bf16_nt<<<dim3(ROWS / 128, (DXBC + 127) / 128), 256, 0, stream>>>(
        ubf, W1bf + (size_t)DINNER * DMODEL, xbcdt, ROWS, DXBC, DMODEL, DXBC);

    conv_kernel<<<dim3((CONVDIM + 255) / 256, ROWS), 256, 0, stream>>>(
        xbcdt, conv_w, conv_b, xbuf, Bmb, Cmb);

    dt_kernel<<<(ROWS * NHEADS + 255) / 256, 256, 0, stream>>>(xbcdt, dt_bias, A_log, dtb, dAb);

    if (chunked) {
        chunkdecay_kernel<<<(BATCH * NHEADS * NCHUNK + 255) / 256, 256, 0, stream>>>(dAb, Pkb);
        scan_phase1<<<BATCH * NHEADS * NCHUNK * 8, 256, 0, stream>>>(
            xbuf, Bmb, dtb, dAb, Sloc);
        scan_phase2<<<BATCH * NHEADS * 32, 256, 0, stream>>>(Sloc, Pkb);
        scan_phase3<<<BATCH * NHEADS * NCHUNK * 8, 256, 0, stream>>>(
            xbuf, Bmb, Cmb, dtb, dAb, Dp, Sloc, ybuf);
    } else {
        scan_kernel<<<BATCH * NHEADS * 8, 256, 0, stream>>>(
            xbuf, Bmb, Cmb, dtb, dAb, Dp, ybuf);
    }

    gate_rms_kernel<<<ROWS, 256, 0, stream>>>(ybuf, zbuf, norm_w, gbf);

    gemm_bf16_nt<<<dim3(ROWS / 128, DMODEL / 128), 256, 0, stream>>>(
        gbf, W2bf, out, ROWS, DMODEL, DINNER, DMODEL);
}

// Round 6
// 517.806 us; speedup vs baseline: 2.3865x; 1.1720x over previous
//
#include <hip/hip_runtime.h>
#include <hip/hip_bf16.h>
#include <stdint.h>

#define BATCH   2
#define SEQLEN  4096
#define DMODEL  768
#define DSTATE  64
#define DCONV   4
#define HEADDIM 128
#define NHEADS  12
#define DINNER  1536
#define DINPROJ 3212
#define CONVDIM 1664
#define DXBC    1676            // CONVDIM + NHEADS (xBC + dt columns)
#define NPAD1   3328            // 26*128, padded rows of W_in (bf16 copy)
#define ROWS    (BATCH*SEQLEN)  // 8192
#define CHUNK   64
#define NCHUNK  (SEQLEN/CHUNK)  // 64

typedef __bf16 bf16x8 __attribute__((ext_vector_type(8)));
typedef float  f32x4  __attribute__((ext_vector_type(4)));

__device__ __forceinline__ void load_lds16(const void* g, void* l) {
    __builtin_amdgcn_global_load_lds(
        (const __attribute__((address_space(1))) unsigned int*)g,
        (__attribute__((address_space(3))) unsigned int*)l, 16, 0, 0);
}

// ---------------- conversion kernels ----------------
__global__ void cvt_bf16_kernel(const float* __restrict__ src,
                                __hip_bfloat16* __restrict__ dst, int n) {
    int i = (blockIdx.x * blockDim.x + threadIdx.x) * 4;
    if (i + 3 < n) {
        float4 v = *(const float4*)(src + i);
        dst[i + 0] = __float2bfloat16(v.x);
        dst[i + 1] = __float2bfloat16(v.y);
        dst[i + 2] = __float2bfloat16(v.z);
        dst[i + 3] = __float2bfloat16(v.w);
    } else {
        for (; i < n; ++i) dst[i] = __float2bfloat16(src[i]);
    }
}

__global__ void padw1_kernel(const float* __restrict__ src,
                             __hip_bfloat16* __restrict__ dst) {
    int i = blockIdx.x * blockDim.x + threadIdx.x;
    if (i >= NPAD1 * DMODEL) return;
    int r = i / DMODEL;
    float v = (r < DINPROJ) ? src[i] : 0.f;
    dst[i] = __float2bfloat16(v);
}

// ---------------- bf16 MFMA GEMM: C = A(MxK) * Bt(NxK)^T  (m97 structure) ----
__global__ __launch_bounds__(256) void gemm_bf16_nt(
    const __hip_bfloat16* __restrict__ A,
    const __hip_bfloat16* __restrict__ Bt,
    float* __restrict__ C,
    int M, int Nreal, int K, int ldc)
{
    __shared__ __align__(16) __hip_bfloat16 As[128 * 32];
    __shared__ __align__(16) __hip_bfloat16 Bs[128 * 32];
    const int tid  = threadIdx.x;
    const int lane = tid & 63;
    const int wave = tid >> 6;
    const int wm   = wave >> 1;
    const int wn   = wave & 1;
    const int tm   = blockIdx.x * 128;
    const int tn   = blockIdx.y * 128;

    f32x4 acc[4][4] = {};

    const int lrow = tid >> 2;
    const int lk8  = (tid & 3) * 8;
    const __hip_bfloat16* gA0 = A  + (size_t)(tm + lrow)      * K + lk8;
    const __hip_bfloat16* gA1 = A  + (size_t)(tm + lrow + 64) * K + lk8;
    const __hip_bfloat16* gB0 = Bt + (size_t)(tn + lrow)      * K + lk8;
    const __hip_bfloat16* gB1 = Bt + (size_t)(tn + lrow + 64) * K + lk8;
    __hip_bfloat16* sA0 = As + tid * 8;
    __hip_bfloat16* sA1 = As + tid * 8 + 2048;
    __hip_bfloat16* sB0 = Bs + tid * 8;
    __hip_bfloat16* sB1 = Bs + tid * 8 + 2048;

    const int fr = lane & 15;
    const int fk = (lane >> 4) * 8;

    for (int kk = 0; kk < K; kk += 32) {
        load_lds16(gA0 + kk, sA0);
        load_lds16(gA1 + kk, sA1);
        load_lds16(gB0 + kk, sB0);
        load_lds16(gB1 + kk, sB1);
        __syncthreads();
        bf16x8 af[4], bfr[4];
#pragma unroll
        for (int i = 0; i < 4; ++i) {
            af[i]  = *(const bf16x8*)(As + (wm * 64 + i * 16 + fr) * 32 + fk);
            bfr[i] = *(const bf16x8*)(Bs + (wn * 64 + i * 16 + fr) * 32 + fk);
        }
#pragma unroll
        for (int mi = 0; mi < 4; ++mi)
#pragma unroll
            for (int ni = 0; ni < 4; ++ni)
                acc[mi][ni] = __builtin_amdgcn_mfma_f32_16x16x32_bf16(
                    af[mi], bfr[ni], acc[mi][ni], 0, 0, 0);
        __syncthreads();
    }

    const int rq = (lane >> 4) * 4;
#pragma unroll
    for (int mi = 0; mi < 4; ++mi) {
#pragma unroll
        for (int ni = 0; ni < 4; ++ni) {
            int col = tn + wn * 64 + ni * 16 + fr;
            if (col < Nreal) {
                size_t rbase = (size_t)(tm + wm * 64 + mi * 16 + rq) * ldc + col;
#pragma unroll
                for (int j = 0; j < 4; ++j)
                    C[rbase + (size_t)j * ldc] = acc[mi][ni][j];
            }
        }
    }
}

// ---------------- depthwise causal conv (D_CONV=4) + SiLU + split -----------
__global__ void conv_kernel(const float* __restrict__ xbcdt,
                            const float* __restrict__ convw,
                            const float* __restrict__ convb,
                            float* __restrict__ xbuf,
                            float* __restrict__ Bm,
                            float* __restrict__ Cm)
{
    int c = blockIdx.x * 256 + threadIdx.x;
    if (c >= CONVDIM) return;
    int row = blockIdx.y;
    int l = row & (SEQLEN - 1);
    float acc = convb[c];
#pragma unroll
    for (int k = 0; k < 4; ++k) {
        int lt = l - 3 + k;
        if (lt >= 0)
            acc += xbcdt[(size_t)(row - 3 + k) * DXBC + c] * convw[c * 4 + k];
    }
    float v = acc / (1.f + expf(-acc));
    if (c < DINNER)               xbuf[(size_t)row * DINNER + c] = v;
    else if (c < DINNER + DSTATE) Bm[(size_t)row * DSTATE + (c - DINNER)] = v;
    else                          Cm[(size_t)row * DSTATE + (c - DINNER - DSTATE)] = v;
}

// ---------------- dt softplus + dA ----------------
__global__ void dt_kernel(const float* __restrict__ xbcdt,
                          const float* __restrict__ dt_bias,
                          const float* __restrict__ A_log,
                          float* __restrict__ dtb, float* __restrict__ dAb)
{
    int i = blockIdx.x * 256 + threadIdx.x;
    if (i >= ROWS * NHEADS) return;
    int row = i / NHEADS, h = i - row * NHEADS;
    float v = xbcdt[(size_t)row * DXBC + CONVDIM + h] + dt_bias[h];
    float dt = (v > 20.f) ? v : log1pf(expf(v));
    float A = -expf(A_log[h]);
    dtb[i] = dt;
    dAb[i] = expf(dt * A);
}

// ======== chunk state kernel (exact f32, register state, no shuffles) =======
// block = (b,h,k); 128 threads; thread tid owns p=tid, all 64 n-states in regs.
// F[p][n] = local scan of chunk from zero; also Pk = prod dA over chunk.
__global__ __launch_bounds__(128) void chunk_state_f32(
    const float* __restrict__ xbuf, const float* __restrict__ Bm,
    const float* __restrict__ dtb, const float* __restrict__ dAb,
    float* __restrict__ Sloc, float* __restrict__ Pk)
{
    const int blk = blockIdx.x;
    const int k   = blk % NCHUNK;
    const int bh  = blk / NCHUNK;
    const int h   = bh % NHEADS;
    const int b   = bh / NHEADS;
    const int tid = threadIdx.x;           // p
    const size_t row0 = (size_t)b * SEQLEN + k * CHUNK;

    __shared__ __align__(16) float lB[CHUNK][DSTATE];    // 16 KB
    __shared__ __align__(16) float lX[CHUNK][HEADDIM];   // 32 KB
    __shared__ float lDA[CHUNK];
    __shared__ float ldt[CHUNK];

    for (int i = tid; i < CHUNK * DSTATE / 4; i += 128)
        ((float4*)&lB[0][0])[i] = ((const float4*)(Bm + row0 * DSTATE))[i];
    for (int i = tid; i < CHUNK * HEADDIM / 4; i += 128) {
        int t = i >> 5, c = i & 31;
        ((float4*)&lX[t][0])[c] =
            *(const float4*)(xbuf + ((row0 + t) * NHEADS + h) * HEADDIM + c * 4);
    }
    if (tid < CHUNK) {
        lDA[tid] = dAb[(row0 + tid) * NHEADS + h];
        ldt[tid] = dtb[(row0 + tid) * NHEADS + h];
    }
    __syncthreads();

    float s[DSTATE];
#pragma unroll
    for (int n = 0; n < DSTATE; ++n) s[n] = 0.f;

#pragma unroll 2
    for (int t = 0; t < CHUNK; ++t) {
        float da  = lDA[t];
        float dtx = ldt[t] * lX[t][tid];
#pragma unroll
        for (int nq = 0; nq < 16; ++nq) {
            float4 bv = *(const float4*)&lB[t][nq * 4];
            s[nq * 4 + 0] = s[nq * 4 + 0] * da + dtx * bv.x;
            s[nq * 4 + 1] = s[nq * 4 + 1] * da + dtx * bv.y;
            s[nq * 4 + 2] = s[nq * 4 + 2] * da + dtx * bv.z;
            s[nq * 4 + 3] = s[nq * 4 + 3] * da + dtx * bv.w;
        }
    }

    const size_t sbase = (size_t)(bh * NCHUNK + k) * (HEADDIM * DSTATE)
                       + (size_t)tid * DSTATE;
#pragma unroll
    for (int nq = 0; nq < 16; ++nq) {
        float4 v = {s[nq * 4 + 0], s[nq * 4 + 1], s[nq * 4 + 2], s[nq * 4 + 3]};
        *(float4*)(Sloc + sbase + nq * 4) = v;
    }

    if (tid == 0) {
        float p = 1.f;
#pragma unroll 8
        for (int t = 0; t < CHUNK; ++t) p *= lDA[t];
        Pk[bh * NCHUNK + k] = p;
    }
}

// ---------------- scan phase 2: inter-chunk prefix (in-place F -> S_init) --
__global__ __launch_bounds__(256) void scan_phase2(
    float* __restrict__ Sloc, const float* __restrict__ Pk)
{
    int bh = blockIdx.x >> 5;
    int eo = (blockIdx.x & 31) * 256 + threadIdx.x;
    __shared__ float lP[NCHUNK];
    if (threadIdx.x < NCHUNK) lP[threadIdx.x] = Pk[bh * NCHUNK + threadIdx.x];
    __syncthreads();
    float s = 0.f;
    size_t base = (size_t)bh * NCHUNK * 8192 + eo;
#pragma unroll 8
    for (int k = 0; k < NCHUNK; ++k) {
        size_t a = base + (size_t)k * 8192;
        float f = Sloc[a];
        Sloc[a] = s;
        s = s * lP[k] + f;
    }
}

// ======== chunk y kernel (exact f32): seed from S_init, emit y + Dp*x =======
__global__ __launch_bounds__(128) void chunk_y_f32(
    const float* __restrict__ xbuf, const float* __restrict__ Bm,
    const float* __restrict__ Cm, const float* __restrict__ dtb,
    const float* __restrict__ dAb, const float* __restrict__ Dp,
    const float* __restrict__ Sini, float* __restrict__ ybuf)
{
    const int blk = blockIdx.x;
    const int k   = blk % NCHUNK;
    const int bh  = blk / NCHUNK;
    const int h   = bh % NHEADS;
    const int b   = bh / NHEADS;
    const int tid = threadIdx.x;           // p
    const size_t row0 = (size_t)b * SEQLEN + k * CHUNK;

    __shared__ __align__(16) float lB[CHUNK][DSTATE];    // 16 KB
    __shared__ __align__(16) float lC[CHUNK][DSTATE];    // 16 KB
    __shared__ __align__(16) float lX[CHUNK][HEADDIM];   // 32 KB
    __shared__ float lDA[CHUNK];
    __shared__ float ldt[CHUNK];

    for (int i = tid; i < CHUNK * DSTATE / 4; i += 128) {
        ((float4*)&lB[0][0])[i] = ((const float4*)(Bm + row0 * DSTATE))[i];
        ((float4*)&lC[0][0])[i] = ((const float4*)(Cm + row0 * DSTATE))[i];
    }
    for (int i = tid; i < CHUNK * HEADDIM / 4; i += 128) {
        int t = i >> 5, c = i & 31;
        ((float4*)&lX[t][0])[c] =
            *(const float4*)(xbuf + ((row0 + t) * NHEADS + h) * HEADDIM + c * 4);
    }
    if (tid < CHUNK) {
        lDA[tid] = dAb[(row0 + tid) * NHEADS + h];
        ldt[tid] = dtb[(row0 + tid) * NHEADS + h];
    }

    // seed state from S_init (f32)
    float s[DSTATE];
    const size_t sbase = (size_t)(bh * NCHUNK + k) * (HEADDIM * DSTATE)
                       + (size_t)tid * DSTATE;
#pragma unroll
    for (int nq = 0; nq < 16; ++nq) {
        float4 v = *(const float4*)(Sini + sbase + nq * 4);
        s[nq * 4 + 0] = v.x; s[nq * 4 + 1] = v.y;
        s[nq * 4 + 2] = v.z; s[nq * 4 + 3] = v.w;
    }
    const float dph = Dp[h];
    __syncthreads();

#pragma unroll 2
    for (int t = 0; t < CHUNK; ++t) {
        float da  = lDA[t];
        float xv  = lX[t][tid];
        float dtx = ldt[t] * xv;
        float y = 0.f;
#pragma unroll
        for (int nq = 0; nq < 16; ++nq) {
            float4 bv = *(const float4*)&lB[t][nq * 4];
            float4 cv = *(const float4*)&lC[t][nq * 4];
            float v0 = s[nq * 4 + 0] * da + dtx * bv.x;
            float v1 = s[nq * 4 + 1] * da + dtx * bv.y;
            float v2 = s[nq * 4 + 2] * da + dtx * bv.z;
            float v3 = s[nq * 4 + 3] * da + dtx * bv.w;
            s[nq * 4 + 0] = v0; s[nq * 4 + 1] = v1;
            s[nq * 4 + 2] = v2; s[nq * 4 + 3] = v3;
            y += cv.x * v0 + cv.y * v1 + cv.z * v2 + cv.w * v3;
        }
        ybuf[((row0 + t) * NHEADS + h) * HEADDIM + tid] = y + dph * xv;
    }
}

// ---------------- fallback: original monolithic scan ------------------------
#define NT 64
__global__ __launch_bounds__(256) void scan_kernel(
    const float* __restrict__ xbuf, const float* __restrict__ Bm,
    const float* __restrict__ Cm, const float* __restrict__ dtb,
    const float* __restrict__ dAb, const float* __restrict__ Dp,
    float* __restrict__ ybuf)
{
    int blk = blockIdx.x;
    int ps = blk & 7;
    int h  = (blk >> 3) % NHEADS;
    int b  = blk / (NHEADS * 8);
    int p0 = ps * 16;
    int tid = threadIdx.x;
    int pl  = tid >> 4;
    int n0  = (tid & 15) * 4;

    __shared__ __align__(16) float lB[NT][64];
    __shared__ __align__(16) float lC[NT][64];
    __shared__ __align__(16) float lDtx[NT][16];
    __shared__ float lDA[NT];
    __shared__ float lY[NT][16];

    float s0 = 0.f, s1 = 0.f, s2 = 0.f, s3 = 0.f;
    float dph = Dp[h];
    size_t rowbase = (size_t)b * SEQLEN;

    for (int t0 = 0; t0 < SEQLEN; t0 += NT) {
        for (int i = tid; i < NT * 64 / 4; i += 256) {
            ((float4*)&lB[0][0])[i] = ((const float4*)Bm)[(rowbase + t0) * 16 + i];
            ((float4*)&lC[0][0])[i] = ((const float4*)Cm)[(rowbase + t0) * 16 + i];
        }
        for (int i = tid; i < NT * 16; i += 256) {
            int t = i >> 4, pp = i & 15;
            size_t r = rowbase + t0 + t;
            lDtx[t][pp] = dtb[r * NHEADS + h] * xbuf[(r * NHEADS + h) * HEADDIM + p0 + pp];
        }
        if (tid < NT) lDA[tid] = dAb[(rowbase + t0 + tid) * NHEADS + h];
        __syncthreads();

        for (int t = 0; t < NT; ++t) {
            float da  = lDA[t];
            float dtx = lDtx[t][pl];
            const float* bp = &lB[t][n0];
            const float* cp = &lC[t][n0];
            s0 = s0 * da + dtx * bp[0];
            s1 = s1 * da + dtx * bp[1];
            s2 = s2 * da + dtx * bp[2];
            s3 = s3 * da + dtx * bp[3];
            float part = s0 * cp[0] + s1 * cp[1] + s2 * cp[2] + s3 * cp[3];
            part += __shfl_xor(part, 1);
            part += __shfl_xor(part, 2);
            part += __shfl_xor(part, 4);
            part += __shfl_xor(part, 8);
            if ((tid & 15) == 0) lY[t][pl] = part;
        }
        __syncthreads();

        for (int i = tid; i < NT * 16; i += 256) {
            int t = i >> 4, pp = i & 15;
            size_t r = rowbase + t0 + t;
            size_t gi = (r * NHEADS + h) * HEADDIM + p0 + pp;
            ybuf[gi] = lY[t][pp] + dph * xbuf[gi];
        }
        __syncthreads();
    }
}

// ---------------- gate (y * silu(z)) + RMSNorm -> bf16 ----------------------
__global__ __launch_bounds__(256) void gate_rms_kernel(
    const float* __restrict__ ybuf, const float* __restrict__ zbuf,
    const float* __restrict__ norm_w, __hip_bfloat16* __restrict__ gbf)
{
    int row = blockIdx.x;
    int tid = threadIdx.x;
    const float* y = ybuf + (size_t)row * DINNER;
    const float* z = zbuf + (size_t)row * DINNER;
    float g[6];
    float ss = 0.f;
#pragma unroll
    for (int j = 0; j < 6; ++j) {
        int idx = tid + j * 256;
        float zz = z[idx];
        float gv = y[idx] * (zz / (1.f + expf(-zz)));
        g[j] = gv;
        ss += gv * gv;
    }
#pragma unroll
    for (int m = 1; m < 64; m <<= 1) ss += __shfl_xor(ss, m);
    __shared__ float red[4];
    if ((tid & 63) == 0) red[tid >> 6] = ss;
    __syncthreads();
    float tot = red[0] + red[1] + red[2] + red[3];
    float scale = rsqrtf(tot * (1.f / DINNER) + 1e-5f);
#pragma unroll
    for (int j = 0; j < 6; ++j) {
        int idx = tid + j * 256;
        gbf[(size_t)row * DINNER + idx] = __float2bfloat16(g[j] * scale * norm_w[idx]);
    }
}

// ---------------- launch ----------------
extern "C" void kernel_launch(void* const* d_in, const int* in_sizes, int n_in,
                              void* d_out, int out_size, void* d_ws, size_t ws_size,
                              hipStream_t stream)
{
    const float* u       = (const float*)d_in[0];
    const float* W_in    = (const float*)d_in[1];
    const float* conv_w  = (const float*)d_in[2];
    const float* conv_b  = (const float*)d_in[3];
    const float* dt_bias = (const float*)d_in[4];
    const float* A_log   = (const float*)d_in[5];
    const float* Dp      = (const float*)d_in[6];
    const float* norm_w  = (const float*)d_in[7];
    const float* W_out   = (const float*)d_in[8];
    float* out = (float*)d_out;

    char* ws = (char*)d_ws;
    size_t off = 0;
    auto alloc = [&](size_t bytes) {
        char* p = ws + off;
        off += (bytes + 255) & ~(size_t)255;
        return p;
    };
    __hip_bfloat16* ubf  = (__hip_bfloat16*)alloc((size_t)ROWS * DMODEL * 2);
    __hip_bfloat16* W1bf = (__hip_bfloat16*)alloc((size_t)NPAD1 * DMODEL * 2);
    __hip_bfloat16* W2bf = (__hip_bfloat16*)alloc((size_t)DMODEL * DINNER * 2);
    float* zbuf  = (float*)alloc((size_t)ROWS * DINNER * 4);   // z columns
    float* xbcdt = (float*)alloc((size_t)ROWS * DXBC * 4);     // xBC + dt columns
    float* xbuf = (float*)alloc((size_t)ROWS * DINNER * 4);
    float* Bmb  = (float*)alloc((size_t)ROWS * DSTATE * 4);
    float* Cmb  = (float*)alloc((size_t)ROWS * DSTATE * 4);
    float* dtb  = (float*)alloc((size_t)ROWS * NHEADS * 4);
    float* dAb  = (float*)alloc((size_t)ROWS * NHEADS * 4);
    float* ybuf = (float*)alloc((size_t)ROWS * DINNER * 4);
    float* Pkb  = (float*)alloc((size_t)BATCH * NHEADS * NCHUNK * 4);
    __hip_bfloat16* gbf = (__hip_bfloat16*)xbuf;  // reuse: xbuf dead after scan
    // ALIAS: xbcdt (54.9 MB) dead after conv+dt; Sloc (50.3 MB) reuses it.
    float* Sloc = (float*)xbcdt;
    bool chunked = (off <= ws_size);

    cvt_bf16_kernel<<<(ROWS * DMODEL / 4 + 255) / 256, 256, 0, stream>>>(u, ubf, ROWS * DMODEL);
    padw1_kernel<<<(NPAD1 * DMODEL + 255) / 256, 256, 0, stream>>>(W_in, W1bf);
    cvt_bf16_kernel<<<(DMODEL * DINNER / 4 + 255) / 256, 256, 0, stream>>>(W_out, W2bf, DMODEL * DINNER);

    // GEMM1 split: z columns (0..1535) and xBC+dt columns (1536..3211)
    gemm_bf16_nt<<<dim3(ROWS / 128, DINNER / 128), 256, 0, stream>>>(
        ubf, W1bf, zbuf, ROWS, DINNER, DMODEL, DINNER);
    gemm_bf16_nt<<<dim3(ROWS / 128, (DXBC + 127) / 128), 256, 0, stream>>>(
        ubf, W1bf + (size_t)DINNER * DMODEL, xbcdt, ROWS, DXBC, DMODEL, DXBC);

    conv_kernel<<<dim3((CONVDIM + 255) / 256, ROWS), 256, 0, stream>>>(
        xbcdt, conv_w, conv_b, xbuf, Bmb, Cmb);

    dt_kernel<<<(ROWS * NHEADS + 255) / 256, 256, 0, stream>>>(xbcdt, dt_bias, A_log, dtb, dAb);

    if (chunked) {
        chunk_state_f32<<<BATCH * NHEADS * NCHUNK, 128, 0, stream>>>(
            xbuf, Bmb, dtb, dAb, Sloc, Pkb);
        scan_phase2<<<BATCH * NHEADS * 32, 256, 0, stream>>>(Sloc, Pkb);
        chunk_y_f32<<<BATCH * NHEADS * NCHUNK, 128, 0, stream>>>(
            xbuf, Bmb, Cmb, dtb, dAb, Dp, Sloc, ybuf);
    } else {
        scan_kernel<<<BATCH * NHEADS * 8, 256, 0, stream>>>(
            xbuf, Bmb, Cmb, dtb, dAb, Dp, ybuf);
    }

    gate_rms_kernel<<<ROWS, 256, 0, stream>>>(ybuf, zbuf, norm_w, gbf);

    gemm_bf16_nt<<<dim3(ROWS / 128, DMODEL / 128), 256, 0, stream>>>(
        gbf, W2bf, out, ROWS, DMODEL, DINNER, DMODEL);
}

// Round 7
// 373.611 us; speedup vs baseline: 3.3075x; 1.3859x over previous
//
#include <hip/hip_runtime.h>
#include <hip/hip_bf16.h>
#include <stdint.h>

#define BATCH   2
#define SEQLEN  4096
#define DMODEL  768
#define DSTATE  64
#define DCONV   4
#define HEADDIM 128
#define NHEADS  12
#define DINNER  1536
#define DINPROJ 3212
#define CONVDIM 1664
#define DXBC    1676            // CONVDIM + NHEADS (xBC + dt columns)
#define NPAD1   3328            // 26*128, padded rows of W_in (bf16 copy)
#define ROWS    (BATCH*SEQLEN)  // 8192
#define CHUNK   64
#define NCHUNK  (SEQLEN/CHUNK)  // 64

typedef __bf16 bf16x8 __attribute__((ext_vector_type(8)));
typedef float  f32x4  __attribute__((ext_vector_type(4)));

__device__ __forceinline__ void load_lds16(const void* g, void* l) {
    __builtin_amdgcn_global_load_lds(
        (const __attribute__((address_space(1))) unsigned int*)g,
        (__attribute__((address_space(3))) unsigned int*)l, 16, 0, 0);
}

// ---------------- conversion kernels ----------------
__global__ void cvt_bf16_kernel(const float* __restrict__ src,
                                __hip_bfloat16* __restrict__ dst, int n) {
    int i = (blockIdx.x * blockDim.x + threadIdx.x) * 4;
    if (i + 3 < n) {
        float4 v = *(const float4*)(src + i);
        dst[i + 0] = __float2bfloat16(v.x);
        dst[i + 1] = __float2bfloat16(v.y);
        dst[i + 2] = __float2bfloat16(v.z);
        dst[i + 3] = __float2bfloat16(v.w);
    } else {
        for (; i < n; ++i) dst[i] = __float2bfloat16(src[i]);
    }
}

__global__ void padw1_kernel(const float* __restrict__ src,
                             __hip_bfloat16* __restrict__ dst) {
    int i = blockIdx.x * blockDim.x + threadIdx.x;
    if (i >= NPAD1 * DMODEL) return;
    int r = i / DMODEL;
    float v = (r < DINPROJ) ? src[i] : 0.f;
    dst[i] = __float2bfloat16(v);
}

// ---------------- bf16 MFMA GEMM: C = A(MxK) * Bt(NxK)^T  (m97 structure) ----
__global__ __launch_bounds__(256) void gemm_bf16_nt(
    const __hip_bfloat16* __restrict__ A,
    const __hip_bfloat16* __restrict__ Bt,
    float* __restrict__ C,
    int M, int Nreal, int K, int ldc)
{
    __shared__ __align__(16) __hip_bfloat16 As[128 * 32];
    __shared__ __align__(16) __hip_bfloat16 Bs[128 * 32];
    const int tid  = threadIdx.x;
    const int lane = tid & 63;
    const int wave = tid >> 6;
    const int wm   = wave >> 1;
    const int wn   = wave & 1;
    const int tm   = blockIdx.x * 128;
    const int tn   = blockIdx.y * 128;

    f32x4 acc[4][4] = {};

    const int lrow = tid >> 2;
    const int lk8  = (tid & 3) * 8;
    const __hip_bfloat16* gA0 = A  + (size_t)(tm + lrow)      * K + lk8;
    const __hip_bfloat16* gA1 = A  + (size_t)(tm + lrow + 64) * K + lk8;
    const __hip_bfloat16* gB0 = Bt + (size_t)(tn + lrow)      * K + lk8;
    const __hip_bfloat16* gB1 = Bt + (size_t)(tn + lrow + 64) * K + lk8;
    __hip_bfloat16* sA0 = As + tid * 8;
    __hip_bfloat16* sA1 = As + tid * 8 + 2048;
    __hip_bfloat16* sB0 = Bs + tid * 8;
    __hip_bfloat16* sB1 = Bs + tid * 8 + 2048;

    const int fr = lane & 15;
    const int fk = (lane >> 4) * 8;

    for (int kk = 0; kk < K; kk += 32) {
        load_lds16(gA0 + kk, sA0);
        load_lds16(gA1 + kk, sA1);
        load_lds16(gB0 + kk, sB0);
        load_lds16(gB1 + kk, sB1);
        __syncthreads();
        bf16x8 af[4], bfr[4];
#pragma unroll
        for (int i = 0; i < 4; ++i) {
            af[i]  = *(const bf16x8*)(As + (wm * 64 + i * 16 + fr) * 32 + fk);
            bfr[i] = *(const bf16x8*)(Bs + (wn * 64 + i * 16 + fr) * 32 + fk);
        }
#pragma unroll
        for (int mi = 0; mi < 4; ++mi)
#pragma unroll
            for (int ni = 0; ni < 4; ++ni)
                acc[mi][ni] = __builtin_amdgcn_mfma_f32_16x16x32_bf16(
                    af[mi], bfr[ni], acc[mi][ni], 0, 0, 0);
        __syncthreads();
    }

    const int rq = (lane >> 4) * 4;
#pragma unroll
    for (int mi = 0; mi < 4; ++mi) {
#pragma unroll
        for (int ni = 0; ni < 4; ++ni) {
            int col = tn + wn * 64 + ni * 16 + fr;
            if (col < Nreal) {
                size_t rbase = (size_t)(tm + wm * 64 + mi * 16 + rq) * ldc + col;
#pragma unroll
                for (int j = 0; j < 4; ++j)
                    C[rbase + (size_t)j * ldc] = acc[mi][ni][j];
            }
        }
    }
}

// ---------------- depthwise causal conv (D_CONV=4) + SiLU + split -----------
__global__ void conv_kernel(const float* __restrict__ xbcdt,
                            const float* __restrict__ convw,
                            const float* __restrict__ convb,
                            float* __restrict__ xbuf,
                            float* __restrict__ Bm,
                            float* __restrict__ Cm)
{
    int c = blockIdx.x * 256 + threadIdx.x;
    if (c >= CONVDIM) return;
    int row = blockIdx.y;
    int l = row & (SEQLEN - 1);
    float acc = convb[c];
#pragma unroll
    for (int k = 0; k < 4; ++k) {
        int lt = l - 3 + k;
        if (lt >= 0)
            acc += xbcdt[(size_t)(row - 3 + k) * DXBC + c] * convw[c * 4 + k];
    }
    float v = acc / (1.f + expf(-acc));
    if (c < DINNER)               xbuf[(size_t)row * DINNER + c] = v;
    else if (c < DINNER + DSTATE) Bm[(size_t)row * DSTATE + (c - DINNER)] = v;
    else                          Cm[(size_t)row * DSTATE + (c - DINNER - DSTATE)] = v;
}

// ---------------- dt softplus + dA ----------------
__global__ void dt_kernel(const float* __restrict__ xbcdt,
                          const float* __restrict__ dt_bias,
                          const float* __restrict__ A_log,
                          float* __restrict__ dtb, float* __restrict__ dAb)
{
    int i = blockIdx.x * 256 + threadIdx.x;
    if (i >= ROWS * NHEADS) return;
    int row = i / NHEADS, h = i - row * NHEADS;
    float v = xbcdt[(size_t)row * DXBC + CONVDIM + h] + dt_bias[h];
    float dt = (v > 20.f) ? v : log1pf(expf(v));
    float A = -expf(A_log[h]);
    dtb[i] = dt;
    dAb[i] = expf(dt * A);
}

// ======== chunk state kernel (exact f32, 4-way n-split, 512 thr) ============
// block = (b,h,k); thread = (p = tid>>2, q = tid&3) owns states n = q*16..+15.
__global__ __launch_bounds__(512) void chunk_state_f32(
    const float* __restrict__ xbuf, const float* __restrict__ Bm,
    const float* __restrict__ dtb, const float* __restrict__ dAb,
    float* __restrict__ Sloc, float* __restrict__ Pk)
{
    const int blk = blockIdx.x;
    const int k   = blk % NCHUNK;
    const int bh  = blk / NCHUNK;
    const int h   = bh % NHEADS;
    const int b   = bh / NHEADS;
    const int tid = threadIdx.x;
    const int p   = tid >> 2;
    const int n0  = (tid & 3) * 16;
    const size_t row0 = (size_t)b * SEQLEN + k * CHUNK;

    __shared__ __align__(16) float lB[CHUNK][DSTATE];    // 16 KB
    __shared__ __align__(16) float lX[CHUNK][HEADDIM];   // 32 KB
    __shared__ float lDA[CHUNK];
    __shared__ float ldt[CHUNK];

    for (int i = tid; i < CHUNK * DSTATE / 4; i += 512)
        ((float4*)&lB[0][0])[i] = ((const float4*)(Bm + row0 * DSTATE))[i];
    for (int i = tid; i < CHUNK * HEADDIM / 4; i += 512) {
        int t = i >> 5, c = i & 31;
        ((float4*)&lX[t][0])[c] =
            *(const float4*)(xbuf + ((row0 + t) * NHEADS + h) * HEADDIM + c * 4);
    }
    if (tid < CHUNK) {
        lDA[tid] = dAb[(row0 + tid) * NHEADS + h];
        ldt[tid] = dtb[(row0 + tid) * NHEADS + h];
    }
    __syncthreads();

    float s[16];
#pragma unroll
    for (int n = 0; n < 16; ++n) s[n] = 0.f;

#pragma unroll 4
    for (int t = 0; t < CHUNK; ++t) {
        float da  = lDA[t];
        float dtx = ldt[t] * lX[t][p];
#pragma unroll
        for (int nq = 0; nq < 4; ++nq) {
            float4 bv = *(const float4*)&lB[t][n0 + nq * 4];
            s[nq * 4 + 0] = s[nq * 4 + 0] * da + dtx * bv.x;
            s[nq * 4 + 1] = s[nq * 4 + 1] * da + dtx * bv.y;
            s[nq * 4 + 2] = s[nq * 4 + 2] * da + dtx * bv.z;
            s[nq * 4 + 3] = s[nq * 4 + 3] * da + dtx * bv.w;
        }
    }

    const size_t sbase = (size_t)(bh * NCHUNK + k) * (HEADDIM * DSTATE)
                       + (size_t)p * DSTATE + n0;
#pragma unroll
    for (int nq = 0; nq < 4; ++nq) {
        float4 v = {s[nq * 4 + 0], s[nq * 4 + 1], s[nq * 4 + 2], s[nq * 4 + 3]};
        *(float4*)(Sloc + sbase + nq * 4) = v;
    }

    if (tid == 0) {
        float pr = 1.f;
#pragma unroll 8
        for (int t = 0; t < CHUNK; ++t) pr *= lDA[t];
        Pk[bh * NCHUNK + k] = pr;
    }
}

// ---------------- scan phase 2: inter-chunk prefix (in-place F -> S_init) --
__global__ __launch_bounds__(256) void scan_phase2(
    float* __restrict__ Sloc, const float* __restrict__ Pk)
{
    int bh = blockIdx.x >> 5;
    int eo = (blockIdx.x & 31) * 256 + threadIdx.x;
    __shared__ float lP[NCHUNK];
    if (threadIdx.x < NCHUNK) lP[threadIdx.x] = Pk[bh * NCHUNK + threadIdx.x];
    __syncthreads();
    float s = 0.f;
    size_t base = (size_t)bh * NCHUNK * 8192 + eo;
#pragma unroll 8
    for (int k = 0; k < NCHUNK; ++k) {
        size_t a = base + (size_t)k * 8192;
        float f = Sloc[a];
        Sloc[a] = s;
        s = s * lP[k] + f;
    }
}

// ======== chunk y kernel (exact f32, 4-way n-split, 512 thr) ================
// thread = (p = tid>>2, q = tid&3); y reduced across the quad via 2x shfl_xor.
__global__ __launch_bounds__(512) void chunk_y_f32(
    const float* __restrict__ xbuf, const float* __restrict__ Bm,
    const float* __restrict__ Cm, const float* __restrict__ dtb,
    const float* __restrict__ dAb, const float* __restrict__ Dp,
    const float* __restrict__ Sini, float* __restrict__ ybuf)
{
    const int blk = blockIdx.x;
    const int k   = blk % NCHUNK;
    const int bh  = blk / NCHUNK;
    const int h   = bh % NHEADS;
    const int b   = bh / NHEADS;
    const int tid = threadIdx.x;
    const int p   = tid >> 2;
    const int q   = tid & 3;
    const int n0  = q * 16;
    const size_t row0 = (size_t)b * SEQLEN + k * CHUNK;

    __shared__ __align__(16) float lB[CHUNK][DSTATE];    // 16 KB
    __shared__ __align__(16) float lC[CHUNK][DSTATE];    // 16 KB
    __shared__ __align__(16) float lX[CHUNK][HEADDIM];   // 32 KB
    __shared__ float lDA[CHUNK];
    __shared__ float ldt[CHUNK];

    for (int i = tid; i < CHUNK * DSTATE / 4; i += 512) {
        ((float4*)&lB[0][0])[i] = ((const float4*)(Bm + row0 * DSTATE))[i];
        ((float4*)&lC[0][0])[i] = ((const float4*)(Cm + row0 * DSTATE))[i];
    }
    for (int i = tid; i < CHUNK * HEADDIM / 4; i += 512) {
        int t = i >> 5, c = i & 31;
        ((float4*)&lX[t][0])[c] =
            *(const float4*)(xbuf + ((row0 + t) * NHEADS + h) * HEADDIM + c * 4);
    }
    if (tid < CHUNK) {
        lDA[tid] = dAb[(row0 + tid) * NHEADS + h];
        ldt[tid] = dtb[(row0 + tid) * NHEADS + h];
    }

    // seed this thread's 16 states from S_init (f32)
    float s[16];
    const size_t sbase = (size_t)(bh * NCHUNK + k) * (HEADDIM * DSTATE)
                       + (size_t)p * DSTATE + n0;
#pragma unroll
    for (int nq = 0; nq < 4; ++nq) {
        float4 v = *(const float4*)(Sini + sbase + nq * 4);
        s[nq * 4 + 0] = v.x; s[nq * 4 + 1] = v.y;
        s[nq * 4 + 2] = v.z; s[nq * 4 + 3] = v.w;
    }
    const float dph = Dp[h];
    __syncthreads();

#pragma unroll 4
    for (int t = 0; t < CHUNK; ++t) {
        float da  = lDA[t];
        float xv  = lX[t][p];
        float dtx = ldt[t] * xv;
        float y = 0.f;
#pragma unroll
        for (int nq = 0; nq < 4; ++nq) {
            float4 bv = *(const float4*)&lB[t][n0 + nq * 4];
            float4 cv = *(const float4*)&lC[t][n0 + nq * 4];
            float v0 = s[nq * 4 + 0] * da + dtx * bv.x;
            float v1 = s[nq * 4 + 1] * da + dtx * bv.y;
            float v2 = s[nq * 4 + 2] * da + dtx * bv.z;
            float v3 = s[nq * 4 + 3] * da + dtx * bv.w;
            s[nq * 4 + 0] = v0; s[nq * 4 + 1] = v1;
            s[nq * 4 + 2] = v2; s[nq * 4 + 3] = v3;
            y += cv.x * v0 + cv.y * v1 + cv.z * v2 + cv.w * v3;
        }
        y += __shfl_xor(y, 1);
        y += __shfl_xor(y, 2);
        if (q == 0)
            ybuf[((row0 + t) * NHEADS + h) * HEADDIM + p] = y + dph * xv;
    }
}

// ---------------- fallback: original monolithic scan ------------------------
#define NT 64
__global__ __launch_bounds__(256) void scan_kernel(
    const float* __restrict__ xbuf, const float* __restrict__ Bm,
    const float* __restrict__ Cm, const float* __restrict__ dtb,
    const float* __restrict__ dAb, const float* __restrict__ Dp,
    float* __restrict__ ybuf)
{
    int blk = blockIdx.x;
    int ps = blk & 7;
    int h  = (blk >> 3) % NHEADS;
    int b  = blk / (NHEADS * 8);
    int p0 = ps * 16;
    int tid = threadIdx.x;
    int pl  = tid >> 4;
    int n0  = (tid & 15) * 4;

    __shared__ __align__(16) float lB[NT][64];
    __shared__ __align__(16) float lC[NT][64];
    __shared__ __align__(16) float lDtx[NT][16];
    __shared__ float lDA[NT];
    __shared__ float lY[NT][16];

    float s0 = 0.f, s1 = 0.f, s2 = 0.f, s3 = 0.f;
    float dph = Dp[h];
    size_t rowbase = (size_t)b * SEQLEN;

    for (int t0 = 0; t0 < SEQLEN; t0 += NT) {
        for (int i = tid; i < NT * 64 / 4; i += 256) {
            ((float4*)&lB[0][0])[i] = ((const float4*)Bm)[(rowbase + t0) * 16 + i];
            ((float4*)&lC[0][0])[i] = ((const float4*)Cm)[(rowbase + t0) * 16 + i];
        }
        for (int i = tid; i < NT * 16; i += 256) {
            int t = i >> 4, pp = i & 15;
            size_t r = rowbase + t0 + t;
            lDtx[t][pp] = dtb[r * NHEADS + h] * xbuf[(r * NHEADS + h) * HEADDIM + p0 + pp];
        }
        if (tid < NT) lDA[tid] = dAb[(rowbase + t0 + tid) * NHEADS + h];
        __syncthreads();

        for (int t = 0; t < NT; ++t) {
            float da  = lDA[t];
            float dtx = lDtx[t][pl];
            const float* bp = &lB[t][n0];
            const float* cp = &lC[t][n0];
            s0 = s0 * da + dtx * bp[0];
            s1 = s1 * da + dtx * bp[1];
            s2 = s2 * da + dtx * bp[2];
            s3 = s3 * da + dtx * bp[3];
            float part = s0 * cp[0] + s1 * cp[1] + s2 * cp[2] + s3 * cp[3];
            part += __shfl_xor(part, 1);
            part += __shfl_xor(part, 2);
            part += __shfl_xor(part, 4);
            part += __shfl_xor(part, 8);
            if ((tid & 15) == 0) lY[t][pl] = part;
        }
        __syncthreads();

        for (int i = tid; i < NT * 16; i += 256) {
            int t = i >> 4, pp = i & 15;
            size_t r = rowbase + t0 + t;
            size_t gi = (r * NHEADS + h) * HEADDIM + p0 + pp;
            ybuf[gi] = lY[t][pp] + dph * xbuf[gi];
        }
        __syncthreads();
    }
}

// ---------------- gate (y * silu(z)) + RMSNorm -> bf16 ----------------------
__global__ __launch_bounds__(256) void gate_rms_kernel(
    const float* __restrict__ ybuf, const float* __restrict__ zbuf,
    const float* __restrict__ norm_w, __hip_bfloat16* __restrict__ gbf)
{
    int row = blockIdx.x;
    int tid = threadIdx.x;
    const float* y = ybuf + (size_t)row * DINNER;
    const float* z = zbuf + (size_t)row * DINNER;
    float g[6];
    float ss = 0.f;
#pragma unroll
    for (int j = 0; j < 6; ++j) {
        int idx = tid + j * 256;
        float zz = z[idx];
        float gv = y[idx] * (zz / (1.f + expf(-zz)));
        g[j] = gv;
        ss += gv * gv;
    }
#pragma unroll
    for (int m = 1; m < 64; m <<= 1) ss += __shfl_xor(ss, m);
    __shared__ float red[4];
    if ((tid & 63) == 0) red[tid >> 6] = ss;
    __syncthreads();
    float tot = red[0] + red[1] + red[2] + red[3];
    float scale = rsqrtf(tot * (1.f / DINNER) + 1e-5f);
#pragma unroll
    for (int j = 0; j < 6; ++j) {
        int idx = tid + j * 256;
        gbf[(size_t)row * DINNER + idx] = __float2bfloat16(g[j] * scale * norm_w[idx]);
    }
}

// ---------------- launch ----------------
extern "C" void kernel_launch(void* const* d_in, const int* in_sizes, int n_in,
                              void* d_out, int out_size, void* d_ws, size_t ws_size,
                              hipStream_t stream)
{
    const float* u       = (const float*)d_in[0];
    const float* W_in    = (const float*)d_in[1];
    const float* conv_w  = (const float*)d_in[2];
    const float* conv_b  = (const float*)d_in[3];
    const float* dt_bias = (const float*)d_in[4];
    const float* A_log   = (const float*)d_in[5];
    const float* Dp      = (const float*)d_in[6];
    const float* norm_w  = (const float*)d_in[7];
    const float* W_out   = (const float*)d_in[8];
    float* out = (float*)d_out;

    char* ws = (char*)d_ws;
    size_t off = 0;
    auto alloc = [&](size_t bytes) {
        char* p = ws + off;
        off += (bytes + 255) & ~(size_t)255;
        return p;
    };
    __hip_bfloat16* ubf  = (__hip_bfloat16*)alloc((size_t)ROWS * DMODEL * 2);
    __hip_bfloat16* W1bf = (__hip_bfloat16*)alloc((size_t)NPAD1 * DMODEL * 2);
    __hip_bfloat16* W2bf = (__hip_bfloat16*)alloc((size_t)DMODEL * DINNER * 2);
    float* zbuf  = (float*)alloc((size_t)ROWS * DINNER * 4);   // z columns
    float* xbcdt = (float*)alloc((size_t)ROWS * DXBC * 4);     // xBC + dt columns
    float* xbuf = (float*)alloc((size_t)ROWS * DINNER * 4);
    float* Bmb  = (float*)alloc((size_t)ROWS * DSTATE * 4);
    float* Cmb  = (float*)alloc((size_t)ROWS * DSTATE * 4);
    float* dtb  = (float*)alloc((size_t)ROWS * NHEADS * 4);
    float* dAb  = (float*)alloc((size_t)ROWS * NHEADS * 4);
    float* ybuf = (float*)alloc((size_t)ROWS * DINNER * 4);
    float* Pkb  = (float*)alloc((size_t)BATCH * NHEADS * NCHUNK * 4);
    __hip_bfloat16* gbf = (__hip_bfloat16*)xbuf;  // reuse: xbuf dead after scan
    // ALIAS: xbcdt (54.9 MB) dead after conv+dt; Sloc (50.3 MB) reuses it.
    float* Sloc = (float*)xbcdt;
    bool chunked = (off <= ws_size);

    cvt_bf16_kernel<<<(ROWS * DMODEL / 4 + 255) / 256, 256, 0, stream>>>(u, ubf, ROWS * DMODEL);
    padw1_kernel<<<(NPAD1 * DMODEL + 255) / 256, 256, 0, stream>>>(W_in, W1bf);
    cvt_bf16_kernel<<<(DMODEL * DINNER / 4 + 255) / 256, 256, 0, stream>>>(W_out, W2bf, DMODEL * DINNER);

    // GEMM1 split: z columns (0..1535) and xBC+dt columns (1536..3211)
    gemm_bf16_nt<<<dim3(ROWS / 128, DINNER / 128), 256, 0, stream>>>(
        ubf, W1bf, zbuf, ROWS, DINNER, DMODEL, DINNER);
    gemm_bf16_nt<<<dim3(ROWS / 128, (DXBC + 127) / 128), 256, 0, stream>>>(
        ubf, W1bf + (size_t)DINNER * DMODEL, xbcdt, ROWS, DXBC, DMODEL, DXBC);

    conv_kernel<<<dim3((CONVDIM + 255) / 256, ROWS), 256, 0, stream>>>(
        xbcdt, conv_w, conv_b, xbuf, Bmb, Cmb);

    dt_kernel<<<(ROWS * NHEADS + 255) / 256, 256, 0, stream>>>(xbcdt, dt_bias, A_log, dtb, dAb);

    if (chunked) {
        chunk_state_f32<<<BATCH * NHEADS * NCHUNK, 512, 0, stream>>>(
            xbuf, Bmb, dtb, dAb, Sloc, Pkb);
        scan_phase2<<<BATCH * NHEADS * 32, 256, 0, stream>>>(Sloc, Pkb);
        chunk_y_f32<<<BATCH * NHEADS * NCHUNK, 512, 0, stream>>>(
            xbuf, Bmb, Cmb, dtb, dAb, Dp, Sloc, ybuf);
    } else {
        scan_kernel<<<BATCH * NHEADS * 8, 256, 0, stream>>>(
            xbuf, Bmb, Cmb, dtb, dAb, Dp, ybuf);
    }

    gate_rms_kernel<<<ROWS, 256, 0, stream>>>(ybuf, zbuf, norm_w, gbf);

    gemm_bf16_nt<<<dim3(ROWS / 128, DMODEL / 128), 256, 0, stream>>>(
        gbf, W2bf, out, ROWS, DMODEL, DINNER, DMODEL);
}